// Round 4
// baseline (5505.998 us; speedup 1.0000x reference)
//
#include <hip/hip_runtime.h>
#include <math.h>

// CV-photonic circuit: WIRES=4, LAYERS=2, CUTOFF=10, BATCH=2048.
// R4: kill scratch spill in applyBS (runtime-sz loop dynamically indexed v[]
// -> private-memory scratch -> 2.2 GB HBM writes/dispatch). BS blocks now
// zero-padded to fixed 19x10x10 so all local arrays are const-indexed.
// applyW fiber remap: W-selecting digit is fiber MSD -> wave-uniform W rows.

namespace {

constexpr int NTB = 512;                 // threads per state block (8 waves)
constexpr int SMEM_BYTES = 80384;        // state 80000 + u 320 + red 32 (+pad)
constexpr double THETA = 0.7853981633974483096; // pi/4

struct cxf { float x, y; };
struct cxd { double x, y; };

// ws float layout:
// [0,100)      V   (V[k*10+m], columns are eigenvectors of a+ad)
// [100,1100)   W   (10 real 10x10 matrices, n-major row-major)
// [1100,4900)  BS  cxf[19*100] ZERO-PADDED 10x10 per total-photon block
// [4900,6500)  UL  cxf[8*100] fused layer gates (UL[0] pre-fused with V^T)
// [6656,...)   u   cxf[B*4*10] encoded per-(b,w) vectors

__device__ __forceinline__ cxd gen_squeeze(int i, int j, double zr, double zi){
  if (j == i+2){ double g = 0.5*sqrt((double)((i+1)*(i+2))); return {zr*g, -zi*g}; }
  if (i == j+2){ double g = 0.5*sqrt((double)((j+1)*(j+2))); return {-zr*g, -zi*g}; }
  return {0.0, 0.0};
}
__device__ __forceinline__ cxd gen_disp(int i, int j, double ar, double ai){
  if (i == j+1){ double g = sqrt((double)i); return {ar*g, ai*g}; }
  if (j == i+1){ double g = sqrt((double)j); return {-ar*g, ai*g}; }
  return {0.0, 0.0};
}

// Wave-cooperative fixed-schedule expm: result = exp(M), n x n (n<=10).
// Result ends in the ORIGINAL R buffer. Uniform barriers; `act` gates work.
__device__ void expm_fixed(bool act, int n, cxd* M, cxd* P, cxd* T, cxd* R, int lane){
  const int n2 = n*n;
  if (act){
    for (int e=lane; e<n2; e+=64){ M[e].x *= 0x1p-10; M[e].y *= 0x1p-10; }
    for (int e=lane; e<n2; e+=64){
      P[e] = M[e];
      cxd r = M[e];
      if (e % (n+1) == 0) r.x += 1.0;
      R[e] = r;
    }
  }
  __syncthreads();
  for (int t=2; t<=12; ++t){
    if (act){
      double inv = 1.0/(double)t;
      for (int e=lane; e<n2; e+=64){
        int i = e/n, j = e - i*n;
        double ax=0.0, ay=0.0;
        for (int k=0;k<n;k++){
          cxd p = P[i*n+k], m = M[k*n+j];
          ax += p.x*m.x - p.y*m.y;
          ay += p.x*m.y + p.y*m.x;
        }
        T[e] = {ax*inv, ay*inv};
      }
    }
    __syncthreads();
    { cxd* tmp = P; P = T; T = tmp; }
    if (act){ for (int e=lane; e<n2; e+=64){ R[e].x += P[e].x; R[e].y += P[e].y; } }
    __syncthreads();
  }
  for (int s=0; s<10; ++s){
    if (act){
      for (int e=lane; e<n2; e+=64){
        int i = e/n, j = e - i*n;
        double ax=0.0, ay=0.0;
        for (int k=0;k<n;k++){
          cxd p = R[i*n+k], q = R[k*n+j];
          ax += p.x*q.x - p.y*q.y;
          ay += p.x*q.y + p.y*q.x;
        }
        T[e] = {ax, ay};
      }
    }
    __syncthreads();
    { cxd* tmp = R; R = T; T = tmp; }
    __syncthreads();
  }
}

// ------------- Kernel A: shared gate tables into d_ws (8 blocks) -----------
// Tasks: 0..9 W[n]=exp(lam_n*Q); 10..28 BS block bn=t-10; 29..44 layer S/D.
__global__ __launch_bounds__(256)
void gates_kernel(const float* __restrict__ dmag, const float* __restrict__ dphase,
                  const float* __restrict__ smag, const float* __restrict__ sphase,
                  float* __restrict__ wsf){
  __shared__ double lam[10];
  __shared__ double Vd[100];
  __shared__ double scr[4][4][200];     // [wave][buf] cxd[100]
  __shared__ double layres[16][200];    // S_lay (0..7), D_lay (8..15)
  const int tid = threadIdx.x;
  const int wv = tid >> 6, lane = tid & 63, g = blockIdx.x;
  float* ws_V = wsf;
  float* ws_W = wsf + 100;
  cxf* ws_BS = (cxf*)(wsf + 1100);
  cxf* ws_UL = (cxf*)(wsf + 4900);

  // Eigendecomposition of x = a+ad (every block, redundantly; block 0 exports).
  if (tid < 10){
    double lo = -6.0, hi = 6.0;
    for (int it=0; it<80; ++it){
      double mid = 0.5*(lo+hi);
      int cnt = 0; double q = 1.0;
      for (int i=0;i<10;i++){
        q = -mid - (i ? (double)i/q : 0.0);
        if (fabs(q) < 1e-300) q = -1e-300;
        if (q < 0.0) cnt++;
      }
      if (cnt > tid) hi = mid; else lo = mid;
    }
    double x = 0.5*(lo+hi);
    double p[10];
    p[0] = 1.0; p[1] = x;
    for (int k=1;k<9;k++) p[k+1] = (x*p[k] - sqrt((double)k)*p[k-1]) * (1.0/sqrt((double)(k+1)));
    double nn=0.0; for (int k=0;k<10;k++) nn += p[k]*p[k];
    double inv = 1.0/sqrt(nn);
    lam[tid] = x;
    for (int k=0;k<10;k++){
      Vd[k*10+tid] = p[k]*inv;
      if (g == 0) ws_V[k*10+tid] = (float)(p[k]*inv);
    }
  }
  __syncthreads();

  const int nrounds = (g==7) ? 5 : 1;
  for (int r=0; r<nrounds; ++r){
    int t;
    if (g < 7) t = 4*g + wv;
    else       t = (r==0) ? ((wv==0) ? 28 : 64) : (29 + (r-1)*4 + wv);
    bool act = (t < 45);
    int n = 10, bn = 0, ilo = 0;
    if (act && t >= 10 && t < 29){
      bn = t - 10; ilo = bn < 10 ? 0 : bn - 9;
      int ihi = bn < 10 ? bn : 9;
      n = ihi - ilo + 1;
    }
    cxd* M = (cxd*)scr[wv][0];
    cxd* P = (cxd*)scr[wv][1];
    cxd* T = (cxd*)scr[wv][2];
    cxd* R = (cxd*)scr[wv][3];
    if (act){
      if (t < 10){
        double l = lam[t];   // Q = -0.5*(a - ad)
        for (int e=lane; e<100; e+=64){
          int i=e/10, j=e-10*i;
          double v = 0.0;
          if (j == i+1) v = -0.5*l*sqrt((double)(i+1));
          else if (i == j+1) v = 0.5*l*sqrt((double)i);
          M[e] = {v, 0.0};
        }
      } else if (t < 29){
        for (int e=lane; e<n*n; e+=64){
          int rr=e/n, c=e-n*rr;
          double v = 0.0;
          if (c == rr+1) v = THETA*sqrt((double)((ilo+rr+1)*(bn-ilo-rr)));
          else if (rr == c+1) v = THETA*sqrt((double)((ilo+c+1)*(bn-ilo-c)));
          M[e] = {0.0, v};
        }
      } else {
        int idx = t-29, kind = idx>>3, L=(idx>>2)&1, w=idx&3;
        double r_ = kind ? (double)dmag[L*4+w]   : (double)smag[L*4+w];
        double ph = kind ? (double)dphase[L*4+w] : (double)sphase[L*4+w];
        double zr = r_*cos(ph), zi = r_*sin(ph);
        for (int e=lane; e<100; e+=64){
          int i=e/10, j=e-10*i;
          M[e] = kind ? gen_disp(i,j,zr,zi) : gen_squeeze(i,j,zr,zi);
        }
      }
    }
    __syncthreads();
    expm_fixed(act, n, M, P, T, R, lane);
    if (act){
      if (t < 10){
        for (int e=lane;e<100;e+=64) ws_W[t*100+e] = (float)R[e].x;
      } else if (t < 29){
        // ZERO-PADDED 10x10 write: entry (rr,c) = R[rr*n+c] if both < n else 0
        for (int e=lane;e<100;e+=64){
          int rr=e/10, c=e-10*rr;
          cxf o; o.x=0.f; o.y=0.f;
          if (rr < n && c < n){ o.x=(float)R[rr*n+c].x; o.y=(float)R[rr*n+c].y; }
          ws_BS[bn*100+e]=o;
        }
      } else {
        int idx = t-29;
        cxd* dst = (cxd*)layres[idx];
        for (int e=lane;e<100;e+=64) dst[e] = R[e];
      }
    }
    __syncthreads();
  }

  if (g == 7){
    // UL[f] = D_lay * S_lay; UL[0] additionally left-multiplied by V^T
    for (int half=0; half<2; ++half){
      int f = wv + half*4;
      cxd* D  = (cxd*)layres[8+f];
      cxd* Sm = (cxd*)layres[f];
      cxd* prod = (cxd*)scr[wv][0];
      for (int e=lane;e<100;e+=64){
        int i=e/10, j=e-10*i;
        double ax=0, ay=0;
        for (int k=0;k<10;k++){
          cxd d=D[i*10+k], s=Sm[k*10+j];
          ax += d.x*s.x - d.y*s.y;
          ay += d.x*s.y + d.y*s.x;
        }
        prod[e] = {ax, ay};
      }
      __syncthreads();
      for (int e=lane;e<100;e+=64){
        int i=e/10, j=e-10*i;
        double ox, oy;
        if (f == 0){
          ox = 0; oy = 0;
          for (int k=0;k<10;k++){
            double v = Vd[k*10+i];           // (V^T)[i][k] = V[k][i]
            ox += v*prod[k*10+j].x;
            oy += v*prod[k*10+j].y;
          }
        } else { ox = prod[e].x; oy = prod[e].y; }
        cxf o; o.x=(float)ox; o.y=(float)oy;
        ws_UL[f*100+e] = o;
      }
      __syncthreads();
    }
  }
}

// ------------- Kernel B: per-(b,w) encoding vector u = D*(S*e0) ------------
__global__ __launch_bounds__(128)
void enc_kernel(const float* __restrict__ jets, const float* __restrict__ sscale,
                float* __restrict__ wsf){
  __shared__ double scr[2][4][200];
  __shared__ double col[20];
  __shared__ double uacc[20];
  const int tid = threadIdx.x, wv = tid>>6, lane = tid&63;
  const int blk = blockIdx.x, b = blk>>2, w = blk&3;

  double eta = (double)jets[b*12 + w*3 + 0];
  double jph = (double)jets[b*12 + w*3 + 1];
  double pt  = (double)jets[b*12 + w*3 + 2];

  cxd* M = (cxd*)scr[wv][0];
  cxd* P = (cxd*)scr[wv][1];
  cxd* T = (cxd*)scr[wv][2];
  cxd* R = (cxd*)scr[wv][3];
  {
    double zr, zi;
    if (wv == 0){ double phs = pt*jph*0.5; zr = eta*cos(phs); zi = eta*sin(phs); }
    else {
      double sc = 10.0/(1.0 + exp(-(double)sscale[0])) + 0.01;
      double mag = sc*pt; zr = mag*cos(eta); zi = mag*sin(eta);
    }
    for (int e=lane; e<100; e+=64){
      int i=e/10, j=e-10*i;
      M[e] = wv ? gen_disp(i,j,zr,zi) : gen_squeeze(i,j,zr,zi);
    }
  }
  __syncthreads();
  expm_fixed(true, 10, M, P, T, R, lane);
  // col = squeeze column 0
  cxd* Rs = (cxd*)scr[0][3];
  cxd* Rd = (cxd*)scr[1][3];
  if (tid < 10){ col[2*tid] = Rs[tid*10].x; col[2*tid+1] = Rs[tid*10].y; }
  __syncthreads();
  if (tid < 10){
    double ax=0, ay=0;
    for (int k=0;k<10;k++){
      cxd d = Rd[tid*10+k];
      double cr = col[2*k], ci = col[2*k+1];
      ax += d.x*cr - d.y*ci;
      ay += d.x*ci + d.y*cr;
    }
    uacc[2*tid] = ax; uacc[2*tid+1] = ay;
  }
  __syncthreads();
  if (tid < 10){
    double rx, ry;
    if (w == 0){
      rx = 0; ry = 0;
      for (int k=0;k<10;k++){
        double v = (double)wsf[k*10 + tid];   // (V^T)[tid][k] = V[k][tid]
        rx += v*uacc[2*k];
        ry += v*uacc[2*k+1];
      }
    } else { rx = uacc[2*tid]; ry = uacc[2*tid+1]; }
    float* u_out = wsf + 6656 + (b*40 + w*10 + tid)*2;
    u_out[0] = (float)rx;
    u_out[1] = (float)ry;
  }
}

// ---------------- Kernel C: the circuit, state-only LDS --------------------

// Single-mode complex gate (matrix from global, wave-uniform -> scalar loads).
__device__ __forceinline__ void apply1_c(cxf* S, const cxf* __restrict__ U, int m, int tid){
  const int sm = (m==0)?1000:((m==1)?100:((m==2)?10:1));
  const int r0 = (m==0)?1:0, r1=(m<=1)?2:1, r2=(m<=2)?3:2;
  const int s0 = (r0==0)?1000:((r0==1)?100:((r0==2)?10:1));
  const int s1 = (r1==0)?1000:((r1==1)?100:((r1==2)?10:1));
  const int s2 = (r2==0)?1000:((r2==1)?100:((r2==2)?10:1));
  for (int f0=0; f0<1024; f0+=NTB){
    int f = f0 + tid;
    if (f < 1000){
      int c0=f/100, rem=f-100*c0, c1=rem/10, c2=rem-10*c1;
      int base = c0*s0 + c1*s1 + c2*s2;
      cxf v[10];
      #pragma unroll
      for (int k=0;k<10;k++) v[k] = S[base + k*sm];
      cxf o[10];
      #pragma unroll
      for (int i=0;i<10;i++){
        float ax=0.f, ay=0.f;
        #pragma unroll
        for (int k=0;k<10;k++){
          cxf u = U[i*10+k];
          ax += u.x*v[k].x - u.y*v[k].y;
          ay += u.x*v[k].y + u.y*v[k].x;
        }
        o[i].x=ax; o[i].y=ay;
      }
      #pragma unroll
      for (int i=0;i<10;i++) S[base + i*sm] = o[i];
    }
  }
}

// Single-mode REAL gate (V or V^T), matrix from global (uniform).
__device__ __forceinline__ void apply1_r(cxf* S, const float* __restrict__ Vm, int m, bool trans, int tid){
  const int sm = (m==0)?1000:((m==1)?100:((m==2)?10:1));
  const int r0 = (m==0)?1:0, r1=(m<=1)?2:1, r2=(m<=2)?3:2;
  const int s0 = (r0==0)?1000:((r0==1)?100:((r0==2)?10:1));
  const int s1 = (r1==0)?1000:((r1==1)?100:((r1==2)?10:1));
  const int s2 = (r2==0)?1000:((r2==1)?100:((r2==2)?10:1));
  for (int f0=0; f0<1024; f0+=NTB){
    int f = f0 + tid;
    if (f < 1000){
      int c0=f/100, rem=f-100*c0, c1=rem/10, c2=rem-10*c1;
      int base = c0*s0 + c1*s1 + c2*s2;
      cxf v[10];
      #pragma unroll
      for (int k=0;k<10;k++) v[k] = S[base + k*sm];
      cxf o[10];
      #pragma unroll
      for (int i=0;i<10;i++){
        float ax=0.f, ay=0.f;
        #pragma unroll
        for (int k=0;k<10;k++){
          float u = trans ? Vm[k*10+i] : Vm[i*10+k];
          ax += u*v[k].x;
          ay += u*v[k].y;
        }
        o[i].x=ax; o[i].y=ay;
      }
      #pragma unroll
      for (int i=0;i<10;i++) S[base + i*sm] = o[i];
    }
  }
}

// Conditional real gate on m2, matrix W[n] selected by m1 coordinate.
// Fiber remap: n (the W selector) is the fiber-index MSD -> wave-uniform rows.
__device__ __forceinline__ void applyW(cxf* S, const float* __restrict__ Wall, int m1, int m2, int tid){
  const int sm2 = (m2==0)?1000:((m2==1)?100:((m2==2)?10:1));
  const int sm1 = (m1==0)?1000:((m1==1)?100:((m1==2)?10:1));
  int ra=-1, rb=-1;
  for (int q=0;q<4;q++) if (q!=m1 && q!=m2){ if (ra<0) ra=q; else rb=q; }
  const int sa = (ra==0)?1000:((ra==1)?100:((ra==2)?10:1));
  const int sb = (rb==0)?1000:((rb==1)?100:((rb==2)?10:1));
  for (int f0=0; f0<1024; f0+=NTB){
    int f = f0 + tid;
    if (f < 1000){
      int n = f/100, rem = f-100*n, qa = rem/10, qb = rem-10*qa;
      int base = n*sm1 + qa*sa + qb*sb;
      const float* __restrict__ Wm = Wall + n*100;
      cxf v[10];
      #pragma unroll
      for (int k=0;k<10;k++) v[k] = S[base + k*sm2];
      cxf o[10];
      #pragma unroll
      for (int i=0;i<10;i++){
        float ax=0.f, ay=0.f;
        #pragma unroll
        for (int k=0;k<10;k++){
          float u = Wm[i*10+k];
          ax += u*v[k].x;
          ay += u*v[k].y;
        }
        o[i].x=ax; o[i].y=ay;
      }
      #pragma unroll
      for (int i=0;i<10;i++) S[base + i*sm2] = o[i];
    }
  }
}

// Beamsplitter via total-photon blocks, ZERO-PADDED 10x10 matrices:
// all local arrays const-indexed -> registers (no scratch).
__device__ __forceinline__ void applyBS(cxf* S, const cxf* __restrict__ BSp, int m1, int m2, int tid){
  int ra=-1, rb=-1;
  for (int q=0;q<4;q++) if (q!=m1 && q!=m2){ if (ra<0) ra=q; else rb=q; }
  const int sa = (ra==0)?1000:((ra==1)?100:((ra==2)?10:1));
  const int sb = (rb==0)?1000:((rb==1)?100:((rb==2)?10:1));
  const int s1 = (m1==0)?1000:((m1==1)?100:((m1==2)?10:1));
  const int s2 = (m2==0)?1000:((m2==1)?100:((m2==2)?10:1));
  for (int w0=0; w0<2048; w0+=NTB){
    int it = w0 + tid;
    if (it < 1900){
      int bn = it/100, rest = it-100*bn;
      int ilo = bn<10?0:bn-9, ihi = bn<10?bn:9, sz = ihi-ilo+1;
      int ca = rest/10, cb = rest-10*ca;
      int base = ca*sa + cb*sb;
      const cxf* __restrict__ Bn = BSp + bn*100;
      cxf v[10];
      #pragma unroll
      for (int c=0;c<10;c++){
        int i = ilo + c;
        cxf t = S[base + ((c<sz) ? (i*s1 + (bn-i)*s2) : 0)];
        v[c].x = (c<sz) ? t.x : 0.f;
        v[c].y = (c<sz) ? t.y : 0.f;
      }
      cxf o[10];
      #pragma unroll
      for (int r=0;r<10;r++){
        float ax=0.f, ay=0.f;
        #pragma unroll
        for (int c=0;c<10;c++){
          cxf u = Bn[r*10+c];               // zero-padded beyond sz
          ax += u.x*v[c].x - u.y*v[c].y;
          ay += u.x*v[c].y + u.y*v[c].x;
        }
        o[r].x=ax; o[r].y=ay;
      }
      #pragma unroll
      for (int r=0;r<10;r++){
        if (r < sz){ int i=ilo+r; S[base + i*s1 + (bn-i)*s2] = o[r]; }
      }
    }
  }
}

__global__ __launch_bounds__(NTB, 4)
void state_kernel(const float* __restrict__ wd, const float* __restrict__ bd,
                  const float* __restrict__ wsf, float* __restrict__ out){
  extern __shared__ __align__(16) char smem[];
  cxf* S    = (cxf*)smem;                 // 10000 cxf (80000 B)
  cxf* uv   = (cxf*)(smem + 80000);       // 4*10 encoding vectors
  float* red = (float*)(smem + 80320);    // 8

  const float* __restrict__ V  = wsf;
  const float* __restrict__ W  = wsf + 100;
  const cxf*   __restrict__ BSm = (const cxf*)(wsf + 1100);
  const cxf*   __restrict__ UL  = (const cxf*)(wsf + 4900);
  const cxf*   __restrict__ uw  = (const cxf*)(wsf + 6656);

  const int tid = threadIdx.x, wv = tid>>6, lane = tid&63;
  const int b = blockIdx.x;

  if (tid < 40) uv[tid] = uw[b*40 + tid];
  __syncthreads();

  // Init: product state S = u0 (x) u1 (x) u2 (x) u3  (V0^T already folded in u0)
  for (int e=tid; e<10000; e+=NTB){
    int c0=e/1000, r_=e-1000*c0, c1=r_/100, r2_=r_-100*c1, c2=r2_/10, c3=r2_-10*c2;
    cxf A = uv[c0], B = uv[10+c1], C = uv[20+c2], D = uv[30+c3];
    float pr = A.x*B.x - A.y*B.y, pi = A.x*B.y + A.y*B.x;
    float qr = pr*C.x - pi*C.y,  qi = pr*C.y + pi*C.x;
    cxf o; o.x = qr*D.x - qi*D.y; o.y = qr*D.y + qi*D.x;
    S[e] = o;
  }
  __syncthreads();

  for (int L=0; L<2; ++L){
    // CX group a=0 (V0^T folded into u0 / UL[0]):
    applyW(S, W, 0, 1, tid); __syncthreads();
    applyW(S, W, 0, 2, tid); __syncthreads();
    applyW(S, W, 0, 3, tid); __syncthreads();
    apply1_r(S, V, 0, false, tid); __syncthreads();
    // a=1:
    apply1_r(S, V, 1, true, tid); __syncthreads();
    applyW(S, W, 1, 2, tid); __syncthreads();
    applyW(S, W, 1, 3, tid); __syncthreads();
    apply1_r(S, V, 1, false, tid); __syncthreads();
    // a=2:
    apply1_r(S, V, 2, true, tid); __syncthreads();
    applyW(S, W, 2, 3, tid); __syncthreads();
    apply1_r(S, V, 2, false, tid); __syncthreads();
    // Beamsplitters:
    applyBS(S, BSm, 0, 1, tid); __syncthreads();
    applyBS(S, BSm, 1, 2, tid); __syncthreads();
    applyBS(S, BSm, 2, 3, tid); __syncthreads();
    applyBS(S, BSm, 3, 0, tid); __syncthreads();
    // Layer single-mode gates (UL[0] carries next layer's V0^T):
    for (int w=0; w<4; ++w){ apply1_c(S, UL + (L*4+w)*100, w, tid); __syncthreads(); }
  }

  float w0 = wd[0], w1 = wd[1], w2 = wd[2];
  float acc = 0.f;
  for (int e=tid; e<10000; e+=NTB){
    cxf z = S[e];
    float p = z.x*z.x + z.y*z.y;
    int n0 = e/1000, r_ = e-1000*n0, n1 = r_/100, r2_ = r_-100*n1, n2 = r2_/10;
    acc += p * ((float)n0*w0 + (float)n1*w1 + (float)n2*w2);
  }
  for (int off=32; off; off>>=1) acc += __shfl_down(acc, off, 64);
  if (lane == 0) red[wv] = acc;
  __syncthreads();
  if (tid == 0){
    float s = 0.f;
    for (int i=0;i<8;i++) s += red[i];
    out[b] = s + bd[0];
  }
}

} // anonymous namespace

extern "C" void kernel_launch(void* const* d_in, const int* in_sizes, int n_in,
                              void* d_out, int out_size, void* d_ws, size_t ws_size,
                              hipStream_t stream){
  const float* jets   = (const float*)d_in[0];
  const float* sscale = (const float*)d_in[1];
  const float* dmag   = (const float*)d_in[2];
  const float* dphase = (const float*)d_in[3];
  const float* smag   = (const float*)d_in[4];
  const float* sphase = (const float*)d_in[5];
  const float* wd     = (const float*)d_in[6];
  const float* bd     = (const float*)d_in[7];
  float* out = (float*)d_out;
  float* wsf = (float*)d_ws;
  int B = in_sizes[0] / 12;

  (void)hipFuncSetAttribute(reinterpret_cast<const void*>(&state_kernel),
                            hipFuncAttributeMaxDynamicSharedMemorySize, SMEM_BYTES);

  gates_kernel<<<8, 256, 0, stream>>>(dmag, dphase, smag, sphase, wsf);
  enc_kernel<<<B*4, 128, 0, stream>>>(jets, sscale, wsf);
  state_kernel<<<B, NTB, SMEM_BYTES, stream>>>(wd, bd, wsf, out);
}

// Round 5
// 4878.415 us; speedup vs baseline: 1.1286x; 1.1286x over previous
//
#include <hip/hip_runtime.h>
#include <math.h>

// CV-photonic circuit: WIRES=4, LAYERS=2, CUTOFF=10, BATCH=2048.
// R5: kill scratch spill for real. R4's fully-unrolled matvecs spilled v[10]/
// o[10] (16.7 GB scratch writes/dispatch, VGPR pinned at 64). Now: k-outer
// matvec (only o[10] acc live), transposed gate tables (contiguous per-k
// rows), #pragma unroll 1 on outer fiber loops, waves_per_eu(4,4) so the
// allocator has the full 128-VGPR budget at 2 blocks/CU (LDS-capped).

namespace {

constexpr int NTB = 512;                 // threads per state block (8 waves)
constexpr int SMEM_BYTES = 80384;        // state 80000 + u 320 + red 32 (+pad)
constexpr double THETA = 0.7853981633974483096; // pi/4

struct cxf { float x, y; };
struct cxd { double x, y; };

// ws float layout (all matrices stored TRANSPOSED for k-outer consumption):
// [0,100)      V    (V[k*10+m] row-major; used directly for the V^T gate)
// [100,200)    VT   (VT[k*10+i] = V[i][k]; used for the V gate)
// [200,1200)   Wt   (10 real 10x10, per-n transposed: Wt[n*100+k*10+i]=W_n[i][k])
// [1200,5000)  BSt  cxf[19*100] zero-padded, transposed: BSt[bn*100+c*10+r]
// [5000,6600)  ULt  cxf[8*100] fused layer gates, transposed
// [6656,...)   u    cxf[B*4*10] encoded per-(b,w) vectors

__device__ __forceinline__ cxd gen_squeeze(int i, int j, double zr, double zi){
  if (j == i+2){ double g = 0.5*sqrt((double)((i+1)*(i+2))); return {zr*g, -zi*g}; }
  if (i == j+2){ double g = 0.5*sqrt((double)((j+1)*(j+2))); return {-zr*g, -zi*g}; }
  return {0.0, 0.0};
}
__device__ __forceinline__ cxd gen_disp(int i, int j, double ar, double ai){
  if (i == j+1){ double g = sqrt((double)i); return {ar*g, ai*g}; }
  if (j == i+1){ double g = sqrt((double)j); return {-ar*g, ai*g}; }
  return {0.0, 0.0};
}

// Wave-cooperative fixed-schedule expm: result = exp(M), n x n (n<=10).
// Result ends in the ORIGINAL R buffer. Uniform barriers; `act` gates work.
__device__ void expm_fixed(bool act, int n, cxd* M, cxd* P, cxd* T, cxd* R, int lane){
  const int n2 = n*n;
  if (act){
    for (int e=lane; e<n2; e+=64){ M[e].x *= 0x1p-10; M[e].y *= 0x1p-10; }
    for (int e=lane; e<n2; e+=64){
      P[e] = M[e];
      cxd r = M[e];
      if (e % (n+1) == 0) r.x += 1.0;
      R[e] = r;
    }
  }
  __syncthreads();
  for (int t=2; t<=12; ++t){
    if (act){
      double inv = 1.0/(double)t;
      for (int e=lane; e<n2; e+=64){
        int i = e/n, j = e - i*n;
        double ax=0.0, ay=0.0;
        for (int k=0;k<n;k++){
          cxd p = P[i*n+k], m = M[k*n+j];
          ax += p.x*m.x - p.y*m.y;
          ay += p.x*m.y + p.y*m.x;
        }
        T[e] = {ax*inv, ay*inv};
      }
    }
    __syncthreads();
    { cxd* tmp = P; P = T; T = tmp; }
    if (act){ for (int e=lane; e<n2; e+=64){ R[e].x += P[e].x; R[e].y += P[e].y; } }
    __syncthreads();
  }
  for (int s=0; s<10; ++s){
    if (act){
      for (int e=lane; e<n2; e+=64){
        int i = e/n, j = e - i*n;
        double ax=0.0, ay=0.0;
        for (int k=0;k<n;k++){
          cxd p = R[i*n+k], q = R[k*n+j];
          ax += p.x*q.x - p.y*q.y;
          ay += p.x*q.y + p.y*q.x;
        }
        T[e] = {ax, ay};
      }
    }
    __syncthreads();
    { cxd* tmp = R; R = T; T = tmp; }
    __syncthreads();
  }
}

// ------------- Kernel A: shared gate tables into d_ws (8 blocks) -----------
// Tasks: 0..9 W[n]=exp(lam_n*Q); 10..28 BS block bn=t-10; 29..44 layer S/D.
__global__ __launch_bounds__(256)
void gates_kernel(const float* __restrict__ dmag, const float* __restrict__ dphase,
                  const float* __restrict__ smag, const float* __restrict__ sphase,
                  float* __restrict__ wsf){
  __shared__ double lam[10];
  __shared__ double Vd[100];
  __shared__ double scr[4][4][200];     // [wave][buf] cxd[100]
  __shared__ double layres[16][200];    // S_lay (0..7), D_lay (8..15)
  const int tid = threadIdx.x;
  const int wv = tid >> 6, lane = tid & 63, g = blockIdx.x;
  float* ws_V  = wsf;
  float* ws_VT = wsf + 100;
  float* ws_W  = wsf + 200;
  cxf* ws_BS = (cxf*)(wsf + 1200);
  cxf* ws_UL = (cxf*)(wsf + 5000);

  // Eigendecomposition of x = a+ad (every block, redundantly; block 0 exports).
  if (tid < 10){
    double lo = -6.0, hi = 6.0;
    for (int it=0; it<80; ++it){
      double mid = 0.5*(lo+hi);
      int cnt = 0; double q = 1.0;
      for (int i=0;i<10;i++){
        q = -mid - (i ? (double)i/q : 0.0);
        if (fabs(q) < 1e-300) q = -1e-300;
        if (q < 0.0) cnt++;
      }
      if (cnt > tid) hi = mid; else lo = mid;
    }
    double x = 0.5*(lo+hi);
    double p[10];
    p[0] = 1.0; p[1] = x;
    for (int k=1;k<9;k++) p[k+1] = (x*p[k] - sqrt((double)k)*p[k-1]) * (1.0/sqrt((double)(k+1)));
    double nn=0.0; for (int k=0;k<10;k++) nn += p[k]*p[k];
    double inv = 1.0/sqrt(nn);
    lam[tid] = x;
    for (int k=0;k<10;k++){
      Vd[k*10+tid] = p[k]*inv;                 // V[k][tid]
      if (g == 0){
        ws_V[k*10+tid]  = (float)(p[k]*inv);   // V row-major
        ws_VT[tid*10+k] = (float)(p[k]*inv);   // VT[tid*10+k] = V[k][tid]
      }
    }
  }
  __syncthreads();

  const int nrounds = (g==7) ? 5 : 1;
  for (int r=0; r<nrounds; ++r){
    int t;
    if (g < 7) t = 4*g + wv;
    else       t = (r==0) ? ((wv==0) ? 28 : 64) : (29 + (r-1)*4 + wv);
    bool act = (t < 45);
    int n = 10, bn = 0, ilo = 0;
    if (act && t >= 10 && t < 29){
      bn = t - 10; ilo = bn < 10 ? 0 : bn - 9;
      int ihi = bn < 10 ? bn : 9;
      n = ihi - ilo + 1;
    }
    cxd* M = (cxd*)scr[wv][0];
    cxd* P = (cxd*)scr[wv][1];
    cxd* T = (cxd*)scr[wv][2];
    cxd* R = (cxd*)scr[wv][3];
    if (act){
      if (t < 10){
        double l = lam[t];   // Q = -0.5*(a - ad)
        for (int e=lane; e<100; e+=64){
          int i=e/10, j=e-10*i;
          double v = 0.0;
          if (j == i+1) v = -0.5*l*sqrt((double)(i+1));
          else if (i == j+1) v = 0.5*l*sqrt((double)i);
          M[e] = {v, 0.0};
        }
      } else if (t < 29){
        for (int e=lane; e<n*n; e+=64){
          int rr=e/n, c=e-n*rr;
          double v = 0.0;
          if (c == rr+1) v = THETA*sqrt((double)((ilo+rr+1)*(bn-ilo-rr)));
          else if (rr == c+1) v = THETA*sqrt((double)((ilo+c+1)*(bn-ilo-c)));
          M[e] = {0.0, v};
        }
      } else {
        int idx = t-29, kind = idx>>3, L=(idx>>2)&1, w=idx&3;
        double r_ = kind ? (double)dmag[L*4+w]   : (double)smag[L*4+w];
        double ph = kind ? (double)dphase[L*4+w] : (double)sphase[L*4+w];
        double zr = r_*cos(ph), zi = r_*sin(ph);
        for (int e=lane; e<100; e+=64){
          int i=e/10, j=e-10*i;
          M[e] = kind ? gen_disp(i,j,zr,zi) : gen_squeeze(i,j,zr,zi);
        }
      }
    }
    __syncthreads();
    expm_fixed(act, n, M, P, T, R, lane);
    if (act){
      if (t < 10){
        // transposed: Wt[t*100 + j*10 + i] = W_t[i][j]
        for (int e=lane;e<100;e+=64){
          int i=e/10, j=e-10*i;
          ws_W[t*100 + j*10 + i] = (float)R[e].x;
        }
      } else if (t < 29){
        // zero-padded AND transposed: BSt[bn*100 + c*10 + rr]
        for (int e=lane;e<100;e+=64){
          int rr=e/10, c=e-10*rr;
          cxf o; o.x=0.f; o.y=0.f;
          if (rr < n && c < n){ o.x=(float)R[rr*n+c].x; o.y=(float)R[rr*n+c].y; }
          ws_BS[bn*100 + c*10 + rr]=o;
        }
      } else {
        int idx = t-29;
        cxd* dst = (cxd*)layres[idx];
        for (int e=lane;e<100;e+=64) dst[e] = R[e];
      }
    }
    __syncthreads();
  }

  if (g == 7){
    // UL[f] = D_lay * S_lay; UL[0] additionally left-multiplied by V^T.
    // Stored transposed: ULt[f*100 + j*10 + i] = UL[i][j].
    for (int half=0; half<2; ++half){
      int f = wv + half*4;
      cxd* D  = (cxd*)layres[8+f];
      cxd* Sm = (cxd*)layres[f];
      cxd* prod = (cxd*)scr[wv][0];
      for (int e=lane;e<100;e+=64){
        int i=e/10, j=e-10*i;
        double ax=0, ay=0;
        for (int k=0;k<10;k++){
          cxd d=D[i*10+k], s=Sm[k*10+j];
          ax += d.x*s.x - d.y*s.y;
          ay += d.x*s.y + d.y*s.x;
        }
        prod[e] = {ax, ay};
      }
      __syncthreads();
      for (int e=lane;e<100;e+=64){
        int i=e/10, j=e-10*i;
        double ox, oy;
        if (f == 0){
          ox = 0; oy = 0;
          for (int k=0;k<10;k++){
            double v = Vd[k*10+i];           // (V^T)[i][k] = V[k][i]
            ox += v*prod[k*10+j].x;
            oy += v*prod[k*10+j].y;
          }
        } else { ox = prod[e].x; oy = prod[e].y; }
        cxf o; o.x=(float)ox; o.y=(float)oy;
        ws_UL[f*100 + j*10 + i] = o;
      }
      __syncthreads();
    }
  }
}

// ------------- Kernel B: per-(b,w) encoding vector u = D*(S*e0) ------------
__global__ __launch_bounds__(128)
void enc_kernel(const float* __restrict__ jets, const float* __restrict__ sscale,
                float* __restrict__ wsf){
  __shared__ double scr[2][4][200];
  __shared__ double col[20];
  __shared__ double uacc[20];
  const int tid = threadIdx.x, wv = tid>>6, lane = tid&63;
  const int blk = blockIdx.x, b = blk>>2, w = blk&3;

  double eta = (double)jets[b*12 + w*3 + 0];
  double jph = (double)jets[b*12 + w*3 + 1];
  double pt  = (double)jets[b*12 + w*3 + 2];

  cxd* M = (cxd*)scr[wv][0];
  cxd* P = (cxd*)scr[wv][1];
  cxd* T = (cxd*)scr[wv][2];
  cxd* R = (cxd*)scr[wv][3];
  {
    double zr, zi;
    if (wv == 0){ double phs = pt*jph*0.5; zr = eta*cos(phs); zi = eta*sin(phs); }
    else {
      double sc = 10.0/(1.0 + exp(-(double)sscale[0])) + 0.01;
      double mag = sc*pt; zr = mag*cos(eta); zi = mag*sin(eta);
    }
    for (int e=lane; e<100; e+=64){
      int i=e/10, j=e-10*i;
      M[e] = wv ? gen_disp(i,j,zr,zi) : gen_squeeze(i,j,zr,zi);
    }
  }
  __syncthreads();
  expm_fixed(true, 10, M, P, T, R, lane);
  // col = squeeze column 0
  cxd* Rs = (cxd*)scr[0][3];
  cxd* Rd = (cxd*)scr[1][3];
  if (tid < 10){ col[2*tid] = Rs[tid*10].x; col[2*tid+1] = Rs[tid*10].y; }
  __syncthreads();
  if (tid < 10){
    double ax=0, ay=0;
    for (int k=0;k<10;k++){
      cxd d = Rd[tid*10+k];
      double cr = col[2*k], ci = col[2*k+1];
      ax += d.x*cr - d.y*ci;
      ay += d.x*ci + d.y*cr;
    }
    uacc[2*tid] = ax; uacc[2*tid+1] = ay;
  }
  __syncthreads();
  if (tid < 10){
    double rx, ry;
    if (w == 0){
      rx = 0; ry = 0;
      for (int k=0;k<10;k++){
        double v = (double)wsf[k*10 + tid];   // (V^T)[tid][k] = V[k][tid]
        rx += v*uacc[2*k];
        ry += v*uacc[2*k+1];
      }
    } else { rx = uacc[2*tid]; ry = uacc[2*tid+1]; }
    float* u_out = wsf + 6656 + (b*40 + w*10 + tid)*2;
    u_out[0] = (float)rx;
    u_out[1] = (float)ry;
  }
}

// ---------------- Kernel C: the circuit, state-only LDS --------------------
// All matvecs k-outer: only the o[10] accumulator is long-lived (~20 VGPR).
// Matrices indexed M[k*10+i] (transposed storage -> contiguous per k).

__device__ __forceinline__ void apply1_c(cxf* S, const cxf* __restrict__ U, int m, int tid){
  const int sm = (m==0)?1000:((m==1)?100:((m==2)?10:1));
  const int r0 = (m==0)?1:0, r1=(m<=1)?2:1, r2=(m<=2)?3:2;
  const int s0 = (r0==0)?1000:((r0==1)?100:((r0==2)?10:1));
  const int s1 = (r1==0)?1000:((r1==1)?100:((r1==2)?10:1));
  const int s2 = (r2==0)?1000:((r2==1)?100:((r2==2)?10:1));
  #pragma unroll 1
  for (int f0=0; f0<1024; f0+=NTB){
    int f = f0 + tid;
    if (f < 1000){
      int c0=f/100, rem=f-100*c0, c1=rem/10, c2=rem-10*c1;
      int base = c0*s0 + c1*s1 + c2*s2;
      float ox[10], oy[10];
      #pragma unroll
      for (int i=0;i<10;i++){ ox[i]=0.f; oy[i]=0.f; }
      #pragma unroll
      for (int k=0;k<10;k++){
        cxf v = S[base + k*sm];
        #pragma unroll
        for (int i=0;i<10;i++){
          cxf u = U[k*10+i];                    // U^T storage: (i,k) entry
          ox[i] += u.x*v.x - u.y*v.y;
          oy[i] += u.x*v.y + u.y*v.x;
        }
      }
      #pragma unroll
      for (int i=0;i<10;i++){ cxf o{ox[i],oy[i]}; S[base + i*sm] = o; }
    }
  }
}

// Real gate; M indexed M[k*10+i]. Pass ws_V for the V^T gate, ws_VT for V.
__device__ __forceinline__ void apply1_r(cxf* S, const float* __restrict__ Mt, int m, int tid){
  const int sm = (m==0)?1000:((m==1)?100:((m==2)?10:1));
  const int r0 = (m==0)?1:0, r1=(m<=1)?2:1, r2=(m<=2)?3:2;
  const int s0 = (r0==0)?1000:((r0==1)?100:((r0==2)?10:1));
  const int s1 = (r1==0)?1000:((r1==1)?100:((r1==2)?10:1));
  const int s2 = (r2==0)?1000:((r2==1)?100:((r2==2)?10:1));
  #pragma unroll 1
  for (int f0=0; f0<1024; f0+=NTB){
    int f = f0 + tid;
    if (f < 1000){
      int c0=f/100, rem=f-100*c0, c1=rem/10, c2=rem-10*c1;
      int base = c0*s0 + c1*s1 + c2*s2;
      float ox[10], oy[10];
      #pragma unroll
      for (int i=0;i<10;i++){ ox[i]=0.f; oy[i]=0.f; }
      #pragma unroll
      for (int k=0;k<10;k++){
        cxf v = S[base + k*sm];
        #pragma unroll
        for (int i=0;i<10;i++){
          float u = Mt[k*10+i];
          ox[i] += u*v.x;
          oy[i] += u*v.y;
        }
      }
      #pragma unroll
      for (int i=0;i<10;i++){ cxf o{ox[i],oy[i]}; S[base + i*sm] = o; }
    }
  }
}

// Conditional real gate on m2, matrix W[n] selected by m1 coordinate.
// Fiber remap: n is the fiber-index MSD -> near-wave-uniform W rows.
__device__ __forceinline__ void applyW(cxf* S, const float* __restrict__ Wall, int m1, int m2, int tid){
  const int sm2 = (m2==0)?1000:((m2==1)?100:((m2==2)?10:1));
  const int sm1 = (m1==0)?1000:((m1==1)?100:((m1==2)?10:1));
  int ra=-1, rb=-1;
  for (int q=0;q<4;q++) if (q!=m1 && q!=m2){ if (ra<0) ra=q; else rb=q; }
  const int sa = (ra==0)?1000:((ra==1)?100:((ra==2)?10:1));
  const int sb = (rb==0)?1000:((rb==1)?100:((rb==2)?10:1));
  #pragma unroll 1
  for (int f0=0; f0<1024; f0+=NTB){
    int f = f0 + tid;
    if (f < 1000){
      int n = f/100, rem = f-100*n, qa = rem/10, qb = rem-10*qa;
      int base = n*sm1 + qa*sa + qb*sb;
      const float* __restrict__ Wm = Wall + n*100;   // transposed W_n
      float ox[10], oy[10];
      #pragma unroll
      for (int i=0;i<10;i++){ ox[i]=0.f; oy[i]=0.f; }
      #pragma unroll
      for (int k=0;k<10;k++){
        cxf v = S[base + k*sm2];
        #pragma unroll
        for (int i=0;i<10;i++){
          float u = Wm[k*10+i];
          ox[i] += u*v.x;
          oy[i] += u*v.y;
        }
      }
      #pragma unroll
      for (int i=0;i<10;i++){ cxf o{ox[i],oy[i]}; S[base + i*sm2] = o; }
    }
  }
}

// Beamsplitter via total-photon blocks, zero-padded transposed 10x10.
__device__ __forceinline__ void applyBS(cxf* S, const cxf* __restrict__ BSp, int m1, int m2, int tid){
  int ra=-1, rb=-1;
  for (int q=0;q<4;q++) if (q!=m1 && q!=m2){ if (ra<0) ra=q; else rb=q; }
  const int sa = (ra==0)?1000:((ra==1)?100:((ra==2)?10:1));
  const int sb = (rb==0)?1000:((rb==1)?100:((rb==2)?10:1));
  const int s1 = (m1==0)?1000:((m1==1)?100:((m1==2)?10:1));
  const int s2 = (m2==0)?1000:((m2==1)?100:((m2==2)?10:1));
  #pragma unroll 1
  for (int w0=0; w0<2048; w0+=NTB){
    int it = w0 + tid;
    if (it < 1900){
      int bn = it/100, rest = it-100*bn;
      int ilo = bn<10?0:bn-9, ihi = bn<10?bn:9, sz = ihi-ilo+1;
      int ca = rest/10, cb = rest-10*ca;
      int base = ca*sa + cb*sb;
      const cxf* __restrict__ Bt = BSp + bn*100;     // transposed, zero-padded
      float ox[10], oy[10];
      #pragma unroll
      for (int r=0;r<10;r++){ ox[r]=0.f; oy[r]=0.f; }
      #pragma unroll
      for (int c=0;c<10;c++){
        int i = ilo + c;
        cxf v = S[base + ((c<sz) ? (i*s1 + (bn-i)*s2) : 0)];
        float vx = (c<sz) ? v.x : 0.f;
        float vy = (c<sz) ? v.y : 0.f;
        #pragma unroll
        for (int r=0;r<10;r++){
          cxf u = Bt[c*10+r];                        // (r,c) entry
          ox[r] += u.x*vx - u.y*vy;
          oy[r] += u.x*vy + u.y*vx;
        }
      }
      #pragma unroll
      for (int r=0;r<10;r++){
        if (r < sz){ int i=ilo+r; cxf o{ox[r],oy[r]}; S[base + i*s1 + (bn-i)*s2] = o; }
      }
    }
  }
}

__global__ __launch_bounds__(NTB)
__attribute__((amdgpu_waves_per_eu(4,4)))
void state_kernel(const float* __restrict__ wd, const float* __restrict__ bd,
                  const float* __restrict__ wsf, float* __restrict__ out){
  extern __shared__ __align__(16) char smem[];
  cxf* S    = (cxf*)smem;                 // 10000 cxf (80000 B)
  cxf* uv   = (cxf*)(smem + 80000);       // 4*10 encoding vectors
  float* red = (float*)(smem + 80320);    // 8

  const float* __restrict__ V   = wsf;            // for V^T gate
  const float* __restrict__ VT  = wsf + 100;      // for V gate
  const float* __restrict__ W   = wsf + 200;
  const cxf*   __restrict__ BSm = (const cxf*)(wsf + 1200);
  const cxf*   __restrict__ UL  = (const cxf*)(wsf + 5000);
  const cxf*   __restrict__ uw  = (const cxf*)(wsf + 6656);

  const int tid = threadIdx.x, wv = tid>>6, lane = tid&63;
  const int b = blockIdx.x;

  if (tid < 40) uv[tid] = uw[b*40 + tid];
  __syncthreads();

  // Init: product state S = u0 (x) u1 (x) u2 (x) u3  (V0^T already folded in u0)
  for (int e=tid; e<10000; e+=NTB){
    int c0=e/1000, r_=e-1000*c0, c1=r_/100, r2_=r_-100*c1, c2=r2_/10, c3=r2_-10*c2;
    cxf A = uv[c0], B = uv[10+c1], C = uv[20+c2], D = uv[30+c3];
    float pr = A.x*B.x - A.y*B.y, pi = A.x*B.y + A.y*B.x;
    float qr = pr*C.x - pi*C.y,  qi = pr*C.y + pi*C.x;
    cxf o; o.x = qr*D.x - qi*D.y; o.y = qr*D.y + qi*D.x;
    S[e] = o;
  }
  __syncthreads();

  for (int L=0; L<2; ++L){
    // CX group a=0 (V0^T folded into u0 / UL[0]):
    applyW(S, W, 0, 1, tid); __syncthreads();
    applyW(S, W, 0, 2, tid); __syncthreads();
    applyW(S, W, 0, 3, tid); __syncthreads();
    apply1_r(S, VT, 0, tid); __syncthreads();      // V gate
    // a=1:
    apply1_r(S, V, 1, tid);  __syncthreads();      // V^T gate
    applyW(S, W, 1, 2, tid); __syncthreads();
    applyW(S, W, 1, 3, tid); __syncthreads();
    apply1_r(S, VT, 1, tid); __syncthreads();
    // a=2:
    apply1_r(S, V, 2, tid);  __syncthreads();
    applyW(S, W, 2, 3, tid); __syncthreads();
    apply1_r(S, VT, 2, tid); __syncthreads();
    // Beamsplitters:
    applyBS(S, BSm, 0, 1, tid); __syncthreads();
    applyBS(S, BSm, 1, 2, tid); __syncthreads();
    applyBS(S, BSm, 2, 3, tid); __syncthreads();
    applyBS(S, BSm, 3, 0, tid); __syncthreads();
    // Layer single-mode gates (UL[0] carries next layer's V0^T):
    for (int w=0; w<4; ++w){ apply1_c(S, UL + (L*4+w)*100, w, tid); __syncthreads(); }
  }

  float w0 = wd[0], w1 = wd[1], w2 = wd[2];
  float acc = 0.f;
  for (int e=tid; e<10000; e+=NTB){
    cxf z = S[e];
    float p = z.x*z.x + z.y*z.y;
    int n0 = e/1000, r_ = e-1000*n0, n1 = r_/100, r2_ = r_-100*n1, n2 = r2_/10;
    acc += p * ((float)n0*w0 + (float)n1*w1 + (float)n2*w2);
  }
  for (int off=32; off; off>>=1) acc += __shfl_down(acc, off, 64);
  if (lane == 0) red[wv] = acc;
  __syncthreads();
  if (tid == 0){
    float s = 0.f;
    for (int i=0;i<8;i++) s += red[i];
    out[b] = s + bd[0];
  }
}

} // anonymous namespace

extern "C" void kernel_launch(void* const* d_in, const int* in_sizes, int n_in,
                              void* d_out, int out_size, void* d_ws, size_t ws_size,
                              hipStream_t stream){
  const float* jets   = (const float*)d_in[0];
  const float* sscale = (const float*)d_in[1];
  const float* dmag   = (const float*)d_in[2];
  const float* dphase = (const float*)d_in[3];
  const float* smag   = (const float*)d_in[4];
  const float* sphase = (const float*)d_in[5];
  const float* wd     = (const float*)d_in[6];
  const float* bd     = (const float*)d_in[7];
  float* out = (float*)d_out;
  float* wsf = (float*)d_ws;
  int B = in_sizes[0] / 12;

  (void)hipFuncSetAttribute(reinterpret_cast<const void*>(&state_kernel),
                            hipFuncAttributeMaxDynamicSharedMemorySize, SMEM_BYTES);

  gates_kernel<<<8, 256, 0, stream>>>(dmag, dphase, smag, sphase, wsf);
  enc_kernel<<<B*4, 128, 0, stream>>>(jets, sscale, wsf);
  state_kernel<<<B, NTB, SMEM_BYTES, stream>>>(wd, bd, wsf, out);
}

// Round 6
// 4875.213 us; speedup vs baseline: 1.1294x; 1.0007x over previous
//
#include <hip/hip_runtime.h>
#include <math.h>

// CV-photonic circuit: WIRES=4, LAYERS=2, CUTOFF=10, BATCH=2048.
// R6: eliminate local ARRAYS entirely in the state kernel's gate bodies.
// R4/R5's 16.7 GB of HBM writes were the AMDGPU PromoteAlloca pass leaving
// ox[]/oy[] (and friends) as scratch allocas; named scalars cannot be
// indexed, so they MUST live in VGPRs. Macro-generated 10-wide matvecs.

namespace {

constexpr int NTB = 512;                 // threads per state block (8 waves)
constexpr int SMEM_BYTES = 80384;        // state 80000 + u 320 + red 32 (+pad)
constexpr double THETA = 0.7853981633974483096; // pi/4

struct cxf { float x, y; };
struct cxd { double x, y; };

// ws float layout (matrices stored TRANSPOSED for k-outer consumption):
// [0,100)      V    (V[k*10+m] row-major; used directly for the V^T gate)
// [100,200)    VT   (VT[k*10+i] = V[i][k]; used for the V gate)
// [200,1200)   Wt   (10 real 10x10, per-n transposed: Wt[n*100+k*10+i]=W_n[i][k])
// [1200,5000)  BSt  cxf[19*100] zero-padded, transposed: BSt[bn*100+c*10+r]
// [5000,6600)  ULt  cxf[8*100] fused layer gates, transposed
// [6656,...)   u    cxf[B*4*10] encoded per-(b,w) vectors

__device__ __forceinline__ cxd gen_squeeze(int i, int j, double zr, double zi){
  if (j == i+2){ double g = 0.5*sqrt((double)((i+1)*(i+2))); return {zr*g, -zi*g}; }
  if (i == j+2){ double g = 0.5*sqrt((double)((j+1)*(j+2))); return {-zr*g, -zi*g}; }
  return {0.0, 0.0};
}
__device__ __forceinline__ cxd gen_disp(int i, int j, double ar, double ai){
  if (i == j+1){ double g = sqrt((double)i); return {ar*g, ai*g}; }
  if (j == i+1){ double g = sqrt((double)j); return {-ar*g, ai*g}; }
  return {0.0, 0.0};
}

// Wave-cooperative fixed-schedule expm: result = exp(M), n x n (n<=10).
__device__ void expm_fixed(bool act, int n, cxd* M, cxd* P, cxd* T, cxd* R, int lane){
  const int n2 = n*n;
  if (act){
    for (int e=lane; e<n2; e+=64){ M[e].x *= 0x1p-10; M[e].y *= 0x1p-10; }
    for (int e=lane; e<n2; e+=64){
      P[e] = M[e];
      cxd r = M[e];
      if (e % (n+1) == 0) r.x += 1.0;
      R[e] = r;
    }
  }
  __syncthreads();
  for (int t=2; t<=12; ++t){
    if (act){
      double inv = 1.0/(double)t;
      for (int e=lane; e<n2; e+=64){
        int i = e/n, j = e - i*n;
        double ax=0.0, ay=0.0;
        for (int k=0;k<n;k++){
          cxd p = P[i*n+k], m = M[k*n+j];
          ax += p.x*m.x - p.y*m.y;
          ay += p.x*m.y + p.y*m.x;
        }
        T[e] = {ax*inv, ay*inv};
      }
    }
    __syncthreads();
    { cxd* tmp = P; P = T; T = tmp; }
    if (act){ for (int e=lane; e<n2; e+=64){ R[e].x += P[e].x; R[e].y += P[e].y; } }
    __syncthreads();
  }
  for (int s=0; s<10; ++s){
    if (act){
      for (int e=lane; e<n2; e+=64){
        int i = e/n, j = e - i*n;
        double ax=0.0, ay=0.0;
        for (int k=0;k<n;k++){
          cxd p = R[i*n+k], q = R[k*n+j];
          ax += p.x*q.x - p.y*q.y;
          ay += p.x*q.y + p.y*q.x;
        }
        T[e] = {ax, ay};
      }
    }
    __syncthreads();
    { cxd* tmp = R; R = T; T = tmp; }
    __syncthreads();
  }
}

// ------------- Kernel A: shared gate tables into d_ws (8 blocks) -----------
__global__ __launch_bounds__(256)
void gates_kernel(const float* __restrict__ dmag, const float* __restrict__ dphase,
                  const float* __restrict__ smag, const float* __restrict__ sphase,
                  float* __restrict__ wsf){
  __shared__ double lam[10];
  __shared__ double Vd[100];
  __shared__ double scr[4][4][200];     // [wave][buf] cxd[100]
  __shared__ double layres[16][200];    // S_lay (0..7), D_lay (8..15)
  const int tid = threadIdx.x;
  const int wv = tid >> 6, lane = tid & 63, g = blockIdx.x;
  float* ws_V  = wsf;
  float* ws_VT = wsf + 100;
  float* ws_W  = wsf + 200;
  cxf* ws_BS = (cxf*)(wsf + 1200);
  cxf* ws_UL = (cxf*)(wsf + 5000);

  if (tid < 10){
    double lo = -6.0, hi = 6.0;
    for (int it=0; it<80; ++it){
      double mid = 0.5*(lo+hi);
      int cnt = 0; double q = 1.0;
      for (int i=0;i<10;i++){
        q = -mid - (i ? (double)i/q : 0.0);
        if (fabs(q) < 1e-300) q = -1e-300;
        if (q < 0.0) cnt++;
      }
      if (cnt > tid) hi = mid; else lo = mid;
    }
    double x = 0.5*(lo+hi);
    double p[10];
    p[0] = 1.0; p[1] = x;
    for (int k=1;k<9;k++) p[k+1] = (x*p[k] - sqrt((double)k)*p[k-1]) * (1.0/sqrt((double)(k+1)));
    double nn=0.0; for (int k=0;k<10;k++) nn += p[k]*p[k];
    double inv = 1.0/sqrt(nn);
    lam[tid] = x;
    for (int k=0;k<10;k++){
      Vd[k*10+tid] = p[k]*inv;
      if (g == 0){
        ws_V[k*10+tid]  = (float)(p[k]*inv);
        ws_VT[tid*10+k] = (float)(p[k]*inv);
      }
    }
  }
  __syncthreads();

  const int nrounds = (g==7) ? 5 : 1;
  for (int r=0; r<nrounds; ++r){
    int t;
    if (g < 7) t = 4*g + wv;
    else       t = (r==0) ? ((wv==0) ? 28 : 64) : (29 + (r-1)*4 + wv);
    bool act = (t < 45);
    int n = 10, bn = 0, ilo = 0;
    if (act && t >= 10 && t < 29){
      bn = t - 10; ilo = bn < 10 ? 0 : bn - 9;
      int ihi = bn < 10 ? bn : 9;
      n = ihi - ilo + 1;
    }
    cxd* M = (cxd*)scr[wv][0];
    cxd* P = (cxd*)scr[wv][1];
    cxd* T = (cxd*)scr[wv][2];
    cxd* R = (cxd*)scr[wv][3];
    if (act){
      if (t < 10){
        double l = lam[t];   // Q = -0.5*(a - ad)
        for (int e=lane; e<100; e+=64){
          int i=e/10, j=e-10*i;
          double v = 0.0;
          if (j == i+1) v = -0.5*l*sqrt((double)(i+1));
          else if (i == j+1) v = 0.5*l*sqrt((double)i);
          M[e] = {v, 0.0};
        }
      } else if (t < 29){
        for (int e=lane; e<n*n; e+=64){
          int rr=e/n, c=e-n*rr;
          double v = 0.0;
          if (c == rr+1) v = THETA*sqrt((double)((ilo+rr+1)*(bn-ilo-rr)));
          else if (rr == c+1) v = THETA*sqrt((double)((ilo+c+1)*(bn-ilo-c)));
          M[e] = {0.0, v};
        }
      } else {
        int idx = t-29, kind = idx>>3, L=(idx>>2)&1, w=idx&3;
        double r_ = kind ? (double)dmag[L*4+w]   : (double)smag[L*4+w];
        double ph = kind ? (double)dphase[L*4+w] : (double)sphase[L*4+w];
        double zr = r_*cos(ph), zi = r_*sin(ph);
        for (int e=lane; e<100; e+=64){
          int i=e/10, j=e-10*i;
          M[e] = kind ? gen_disp(i,j,zr,zi) : gen_squeeze(i,j,zr,zi);
        }
      }
    }
    __syncthreads();
    expm_fixed(act, n, M, P, T, R, lane);
    if (act){
      if (t < 10){
        for (int e=lane;e<100;e+=64){
          int i=e/10, j=e-10*i;
          ws_W[t*100 + j*10 + i] = (float)R[e].x;   // transposed
        }
      } else if (t < 29){
        for (int e=lane;e<100;e+=64){
          int rr=e/10, c=e-10*rr;
          cxf o; o.x=0.f; o.y=0.f;
          if (rr < n && c < n){ o.x=(float)R[rr*n+c].x; o.y=(float)R[rr*n+c].y; }
          ws_BS[bn*100 + c*10 + rr]=o;              // zero-padded + transposed
        }
      } else {
        int idx = t-29;
        cxd* dst = (cxd*)layres[idx];
        for (int e=lane;e<100;e+=64) dst[e] = R[e];
      }
    }
    __syncthreads();
  }

  if (g == 7){
    for (int half=0; half<2; ++half){
      int f = wv + half*4;
      cxd* D  = (cxd*)layres[8+f];
      cxd* Sm = (cxd*)layres[f];
      cxd* prod = (cxd*)scr[wv][0];
      for (int e=lane;e<100;e+=64){
        int i=e/10, j=e-10*i;
        double ax=0, ay=0;
        for (int k=0;k<10;k++){
          cxd d=D[i*10+k], s=Sm[k*10+j];
          ax += d.x*s.x - d.y*s.y;
          ay += d.x*s.y + d.y*s.x;
        }
        prod[e] = {ax, ay};
      }
      __syncthreads();
      for (int e=lane;e<100;e+=64){
        int i=e/10, j=e-10*i;
        double ox, oy;
        if (f == 0){
          ox = 0; oy = 0;
          for (int k=0;k<10;k++){
            double v = Vd[k*10+i];
            ox += v*prod[k*10+j].x;
            oy += v*prod[k*10+j].y;
          }
        } else { ox = prod[e].x; oy = prod[e].y; }
        cxf o; o.x=(float)ox; o.y=(float)oy;
        ws_UL[f*100 + j*10 + i] = o;                // transposed
      }
      __syncthreads();
    }
  }
}

// ------------- Kernel B: per-(b,w) encoding vector u = D*(S*e0) ------------
__global__ __launch_bounds__(128)
void enc_kernel(const float* __restrict__ jets, const float* __restrict__ sscale,
                float* __restrict__ wsf){
  __shared__ double scr[2][4][200];
  __shared__ double col[20];
  __shared__ double uacc[20];
  const int tid = threadIdx.x, wv = tid>>6, lane = tid&63;
  const int blk = blockIdx.x, b = blk>>2, w = blk&3;

  double eta = (double)jets[b*12 + w*3 + 0];
  double jph = (double)jets[b*12 + w*3 + 1];
  double pt  = (double)jets[b*12 + w*3 + 2];

  cxd* M = (cxd*)scr[wv][0];
  cxd* P = (cxd*)scr[wv][1];
  cxd* T = (cxd*)scr[wv][2];
  cxd* R = (cxd*)scr[wv][3];
  {
    double zr, zi;
    if (wv == 0){ double phs = pt*jph*0.5; zr = eta*cos(phs); zi = eta*sin(phs); }
    else {
      double sc = 10.0/(1.0 + exp(-(double)sscale[0])) + 0.01;
      double mag = sc*pt; zr = mag*cos(eta); zi = mag*sin(eta);
    }
    for (int e=lane; e<100; e+=64){
      int i=e/10, j=e-10*i;
      M[e] = wv ? gen_disp(i,j,zr,zi) : gen_squeeze(i,j,zr,zi);
    }
  }
  __syncthreads();
  expm_fixed(true, 10, M, P, T, R, lane);
  cxd* Rs = (cxd*)scr[0][3];
  cxd* Rd = (cxd*)scr[1][3];
  if (tid < 10){ col[2*tid] = Rs[tid*10].x; col[2*tid+1] = Rs[tid*10].y; }
  __syncthreads();
  if (tid < 10){
    double ax=0, ay=0;
    for (int k=0;k<10;k++){
      cxd d = Rd[tid*10+k];
      double cr = col[2*k], ci = col[2*k+1];
      ax += d.x*cr - d.y*ci;
      ay += d.x*ci + d.y*cr;
    }
    uacc[2*tid] = ax; uacc[2*tid+1] = ay;
  }
  __syncthreads();
  if (tid < 10){
    double rx, ry;
    if (w == 0){
      rx = 0; ry = 0;
      for (int k=0;k<10;k++){
        double v = (double)wsf[k*10 + tid];
        rx += v*uacc[2*k];
        ry += v*uacc[2*k+1];
      }
    } else { rx = uacc[2*tid]; ry = uacc[2*tid+1]; }
    float* u_out = wsf + 6656 + (b*40 + w*10 + tid)*2;
    u_out[0] = (float)rx;
    u_out[1] = (float)ry;
  }
}

// ---------------- Kernel C: the circuit, state-only LDS --------------------
// NO local arrays: 20 named scalar accumulators per matvec, macro-generated.

#define DECL_ACC \
  float ox0=0.f,oy0=0.f, ox1=0.f,oy1=0.f, ox2=0.f,oy2=0.f, ox3=0.f,oy3=0.f, \
        ox4=0.f,oy4=0.f, ox5=0.f,oy5=0.f, ox6=0.f,oy6=0.f, ox7=0.f,oy7=0.f, \
        ox8=0.f,oy8=0.f, ox9=0.f,oy9=0.f;

// complex update: acc_i += U[(k,i)] * v   (U stored transposed: Ut[k*10+i])
#define CUPD(i,k) { cxf u = U[(k)*10+(i)]; ox##i += u.x*vx - u.y*vy; oy##i += u.x*vy + u.y*vx; }
#define CROW(k) { cxf v = S[base + (k)*sm]; float vx=v.x, vy=v.y; \
  CUPD(0,k) CUPD(1,k) CUPD(2,k) CUPD(3,k) CUPD(4,k) \
  CUPD(5,k) CUPD(6,k) CUPD(7,k) CUPD(8,k) CUPD(9,k) }
#define CALLROWS CROW(0) CROW(1) CROW(2) CROW(3) CROW(4) CROW(5) CROW(6) CROW(7) CROW(8) CROW(9)

// real update
#define RUPD(i,k) { float u = Mt[(k)*10+(i)]; ox##i += u*vx; oy##i += u*vy; }
#define RROW(k) { cxf v = S[base + (k)*sm]; float vx=v.x, vy=v.y; \
  RUPD(0,k) RUPD(1,k) RUPD(2,k) RUPD(3,k) RUPD(4,k) \
  RUPD(5,k) RUPD(6,k) RUPD(7,k) RUPD(8,k) RUPD(9,k) }
#define RALLROWS RROW(0) RROW(1) RROW(2) RROW(3) RROW(4) RROW(5) RROW(6) RROW(7) RROW(8) RROW(9)

#define FSTORE(i) { cxf o; o.x=ox##i; o.y=oy##i; S[base + (i)*sm] = o; }
#define ALLSTORE FSTORE(0) FSTORE(1) FSTORE(2) FSTORE(3) FSTORE(4) FSTORE(5) FSTORE(6) FSTORE(7) FSTORE(8) FSTORE(9)

__device__ __forceinline__ void apply1_c(cxf* S, const cxf* __restrict__ U, int m, int tid){
  const int sm = (m==0)?1000:((m==1)?100:((m==2)?10:1));
  const int r0 = (m==0)?1:0, r1=(m<=1)?2:1, r2=(m<=2)?3:2;
  const int s0 = (r0==0)?1000:((r0==1)?100:((r0==2)?10:1));
  const int s1 = (r1==0)?1000:((r1==1)?100:((r1==2)?10:1));
  const int s2 = (r2==0)?1000:((r2==1)?100:((r2==2)?10:1));
  #pragma unroll 1
  for (int f0=0; f0<1024; f0+=NTB){
    int f = f0 + tid;
    if (f < 1000){
      int c0=f/100, rem=f-100*c0, c1=rem/10, c2=rem-10*c1;
      int base = c0*s0 + c1*s1 + c2*s2;
      DECL_ACC
      CALLROWS
      ALLSTORE
    }
  }
}

// Real gate; Mt indexed Mt[k*10+i]. Pass ws_V for the V^T gate, ws_VT for V.
__device__ __forceinline__ void apply1_r(cxf* S, const float* __restrict__ Mt, int m, int tid){
  const int sm = (m==0)?1000:((m==1)?100:((m==2)?10:1));
  const int r0 = (m==0)?1:0, r1=(m<=1)?2:1, r2=(m<=2)?3:2;
  const int s0 = (r0==0)?1000:((r0==1)?100:((r0==2)?10:1));
  const int s1 = (r1==0)?1000:((r1==1)?100:((r1==2)?10:1));
  const int s2 = (r2==0)?1000:((r2==1)?100:((r2==2)?10:1));
  #pragma unroll 1
  for (int f0=0; f0<1024; f0+=NTB){
    int f = f0 + tid;
    if (f < 1000){
      int c0=f/100, rem=f-100*c0, c1=rem/10, c2=rem-10*c1;
      int base = c0*s0 + c1*s1 + c2*s2;
      DECL_ACC
      RALLROWS
      ALLSTORE
    }
  }
}

// Conditional real gate on m2, W[n] selected by m1 digit (fiber MSD -> near-uniform).
__device__ __forceinline__ void applyW(cxf* S, const float* __restrict__ Wall, int m1, int m2, int tid){
  const int sm  = (m2==0)?1000:((m2==1)?100:((m2==2)?10:1));
  const int sm1 = (m1==0)?1000:((m1==1)?100:((m1==2)?10:1));
  int ra=-1, rb=-1;
  for (int q=0;q<4;q++) if (q!=m1 && q!=m2){ if (ra<0) ra=q; else rb=q; }
  const int sa = (ra==0)?1000:((ra==1)?100:((ra==2)?10:1));
  const int sb = (rb==0)?1000:((rb==1)?100:((rb==2)?10:1));
  #pragma unroll 1
  for (int f0=0; f0<1024; f0+=NTB){
    int f = f0 + tid;
    if (f < 1000){
      int n = f/100, rem = f-100*n, qa = rem/10, qb = rem-10*qa;
      int base = n*sm1 + qa*sa + qb*sb;
      const float* __restrict__ Mt = Wall + n*100;   // transposed W_n
      DECL_ACC
      RALLROWS
      ALLSTORE
    }
  }
}

// Beamsplitter via total-photon blocks, zero-padded transposed 10x10.
#define BUPD(r,c) { cxf u = Bt[(c)*10+(r)]; ox##r += u.x*vx - u.y*vy; oy##r += u.x*vy + u.y*vx; }
#define BROW(c) { int i = ilo+(c); bool in = (c)<sz; \
  cxf v = S[base + (in ? (i*s1 + (bn-i)*s2) : 0)]; \
  float vx = in ? v.x : 0.f, vy = in ? v.y : 0.f; \
  BUPD(0,c) BUPD(1,c) BUPD(2,c) BUPD(3,c) BUPD(4,c) \
  BUPD(5,c) BUPD(6,c) BUPD(7,c) BUPD(8,c) BUPD(9,c) }
#define BALLROWS BROW(0) BROW(1) BROW(2) BROW(3) BROW(4) BROW(5) BROW(6) BROW(7) BROW(8) BROW(9)
#define BSTORE(r) if ((r) < sz){ int i=ilo+(r); cxf o; o.x=ox##r; o.y=oy##r; S[base + i*s1 + (bn-i)*s2] = o; }
#define BALLSTORE BSTORE(0) BSTORE(1) BSTORE(2) BSTORE(3) BSTORE(4) BSTORE(5) BSTORE(6) BSTORE(7) BSTORE(8) BSTORE(9)

__device__ __forceinline__ void applyBS(cxf* S, const cxf* __restrict__ BSp, int m1, int m2, int tid){
  int ra=-1, rb=-1;
  for (int q=0;q<4;q++) if (q!=m1 && q!=m2){ if (ra<0) ra=q; else rb=q; }
  const int sa = (ra==0)?1000:((ra==1)?100:((ra==2)?10:1));
  const int sb = (rb==0)?1000:((rb==1)?100:((rb==2)?10:1));
  const int s1 = (m1==0)?1000:((m1==1)?100:((m1==2)?10:1));
  const int s2 = (m2==0)?1000:((m2==1)?100:((m2==2)?10:1));
  #pragma unroll 1
  for (int w0=0; w0<2048; w0+=NTB){
    int it = w0 + tid;
    if (it < 1900){
      int bn = it/100, rest = it-100*bn;
      int ilo = bn<10?0:bn-9, ihi = bn<10?bn:9, sz = ihi-ilo+1;
      int ca = rest/10, cb = rest-10*ca;
      int base = ca*sa + cb*sb;
      const cxf* __restrict__ Bt = BSp + bn*100;     // transposed, zero-padded
      DECL_ACC
      BALLROWS
      BALLSTORE
    }
  }
}

__global__ __launch_bounds__(NTB)
__attribute__((amdgpu_waves_per_eu(4,4)))
void state_kernel(const float* __restrict__ wd, const float* __restrict__ bd,
                  const float* __restrict__ wsf, float* __restrict__ out){
  extern __shared__ __align__(16) char smem[];
  cxf* S    = (cxf*)smem;                 // 10000 cxf (80000 B)
  cxf* uv   = (cxf*)(smem + 80000);       // 4*10 encoding vectors
  float* red = (float*)(smem + 80320);    // 8

  const float* __restrict__ V   = wsf;            // for V^T gate
  const float* __restrict__ VT  = wsf + 100;      // for V gate
  const float* __restrict__ W   = wsf + 200;
  const cxf*   __restrict__ BSm = (const cxf*)(wsf + 1200);
  const cxf*   __restrict__ UL  = (const cxf*)(wsf + 5000);
  const cxf*   __restrict__ uw  = (const cxf*)(wsf + 6656);

  const int tid = threadIdx.x, wv = tid>>6, lane = tid&63;
  const int b = blockIdx.x;

  if (tid < 40) uv[tid] = uw[b*40 + tid];
  __syncthreads();

  // Init: product state S = u0 (x) u1 (x) u2 (x) u3  (V0^T already folded in u0)
  for (int e=tid; e<10000; e+=NTB){
    int c0=e/1000, r_=e-1000*c0, c1=r_/100, r2_=r_-100*c1, c2=r2_/10, c3=r2_-10*c2;
    cxf A = uv[c0], B = uv[10+c1], C = uv[20+c2], D = uv[30+c3];
    float pr = A.x*B.x - A.y*B.y, pi = A.x*B.y + A.y*B.x;
    float qr = pr*C.x - pi*C.y,  qi = pr*C.y + pi*C.x;
    cxf o; o.x = qr*D.x - qi*D.y; o.y = qr*D.y + qi*D.x;
    S[e] = o;
  }
  __syncthreads();

  for (int L=0; L<2; ++L){
    // CX group a=0 (V0^T folded into u0 / UL[0]):
    applyW(S, W, 0, 1, tid); __syncthreads();
    applyW(S, W, 0, 2, tid); __syncthreads();
    applyW(S, W, 0, 3, tid); __syncthreads();
    apply1_r(S, VT, 0, tid); __syncthreads();      // V gate
    // a=1:
    apply1_r(S, V, 1, tid);  __syncthreads();      // V^T gate
    applyW(S, W, 1, 2, tid); __syncthreads();
    applyW(S, W, 1, 3, tid); __syncthreads();
    apply1_r(S, VT, 1, tid); __syncthreads();
    // a=2:
    apply1_r(S, V, 2, tid);  __syncthreads();
    applyW(S, W, 2, 3, tid); __syncthreads();
    apply1_r(S, VT, 2, tid); __syncthreads();
    // Beamsplitters:
    applyBS(S, BSm, 0, 1, tid); __syncthreads();
    applyBS(S, BSm, 1, 2, tid); __syncthreads();
    applyBS(S, BSm, 2, 3, tid); __syncthreads();
    applyBS(S, BSm, 3, 0, tid); __syncthreads();
    // Layer single-mode gates (UL[0] carries next layer's V0^T):
    for (int w=0; w<4; ++w){ apply1_c(S, UL + (L*4+w)*100, w, tid); __syncthreads(); }
  }

  float w0 = wd[0], w1 = wd[1], w2 = wd[2];
  float acc = 0.f;
  for (int e=tid; e<10000; e+=NTB){
    cxf z = S[e];
    float p = z.x*z.x + z.y*z.y;
    int n0 = e/1000, r_ = e-1000*n0, n1 = r_/100, r2_ = r_-100*n1, n2 = r2_/10;
    acc += p * ((float)n0*w0 + (float)n1*w1 + (float)n2*w2);
  }
  for (int off=32; off; off>>=1) acc += __shfl_down(acc, off, 64);
  if (lane == 0) red[wv] = acc;
  __syncthreads();
  if (tid == 0){
    float s = 0.f;
    for (int i=0;i<8;i++) s += red[i];
    out[b] = s + bd[0];
  }
}

} // anonymous namespace

extern "C" void kernel_launch(void* const* d_in, const int* in_sizes, int n_in,
                              void* d_out, int out_size, void* d_ws, size_t ws_size,
                              hipStream_t stream){
  const float* jets   = (const float*)d_in[0];
  const float* sscale = (const float*)d_in[1];
  const float* dmag   = (const float*)d_in[2];
  const float* dphase = (const float*)d_in[3];
  const float* smag   = (const float*)d_in[4];
  const float* sphase = (const float*)d_in[5];
  const float* wd     = (const float*)d_in[6];
  const float* bd     = (const float*)d_in[7];
  float* out = (float*)d_out;
  float* wsf = (float*)d_ws;
  int B = in_sizes[0] / 12;

  (void)hipFuncSetAttribute(reinterpret_cast<const void*>(&state_kernel),
                            hipFuncAttributeMaxDynamicSharedMemorySize, SMEM_BYTES);

  gates_kernel<<<8, 256, 0, stream>>>(dmag, dphase, smag, sphase, wsf);
  enc_kernel<<<B*4, 128, 0, stream>>>(jets, sscale, wsf);
  state_kernel<<<B, NTB, SMEM_BYTES, stream>>>(wd, bd, wsf, out);
}

// Round 7
// 1889.038 us; speedup vs baseline: 2.9147x; 2.5808x over previous
//
#include <hip/hip_runtime.h>
#include <math.h>

// CV-photonic circuit: WIRES=4, LAYERS=2, CUTOFF=10, BATCH=2048.
// R7: occupancy + code size. NTB 512->1024 (2 blocks/CU = 32 waves/CU, 100%
// occupancy; VGPR capped at 64 via waves_per_eu(8)). Gate bodies ROLLED over
// k with 20 named scalar accumulators (no arrays -> no allocas; ~10x smaller
// instruction stream than R4-R6's full unroll, fits the 32 KB I$).

namespace {

constexpr int NTB = 1024;                // threads per state block (16 waves)
constexpr int SMEM_BYTES = 80384;        // state 80000 + uv 320 + red 64
constexpr double THETA = 0.7853981633974483096; // pi/4

struct cxf { float x, y; };
struct cxd { double x, y; };

// ws float layout (matrices stored TRANSPOSED for k-outer consumption):
// [0,100)      V    (V[k*10+m]; used directly for the V^T gate)
// [100,200)    VT   (VT[k*10+i] = V[i][k]; used for the V gate)
// [200,1200)   Wt   (10 real 10x10, per-n transposed: Wt[n*100+k*10+i]=W_n[i][k])
// [1200,5000)  BSt  cxf[19*100] zero-padded, transposed: BSt[bn*100+c*10+r]
// [5000,6600)  ULt  cxf[8*100] fused layer gates, transposed
// [6656,...)   u    cxf[B*4*10] encoded per-(b,w) vectors

__device__ __forceinline__ cxd gen_squeeze(int i, int j, double zr, double zi){
  if (j == i+2){ double g = 0.5*sqrt((double)((i+1)*(i+2))); return {zr*g, -zi*g}; }
  if (i == j+2){ double g = 0.5*sqrt((double)((j+1)*(j+2))); return {-zr*g, -zi*g}; }
  return {0.0, 0.0};
}
__device__ __forceinline__ cxd gen_disp(int i, int j, double ar, double ai){
  if (i == j+1){ double g = sqrt((double)i); return {ar*g, ai*g}; }
  if (j == i+1){ double g = sqrt((double)j); return {-ar*g, ai*g}; }
  return {0.0, 0.0};
}

// Wave-cooperative fixed-schedule expm: result = exp(M), n x n (n<=10).
__device__ void expm_fixed(bool act, int n, cxd* M, cxd* P, cxd* T, cxd* R, int lane){
  const int n2 = n*n;
  if (act){
    for (int e=lane; e<n2; e+=64){ M[e].x *= 0x1p-10; M[e].y *= 0x1p-10; }
    for (int e=lane; e<n2; e+=64){
      P[e] = M[e];
      cxd r = M[e];
      if (e % (n+1) == 0) r.x += 1.0;
      R[e] = r;
    }
  }
  __syncthreads();
  for (int t=2; t<=12; ++t){
    if (act){
      double inv = 1.0/(double)t;
      for (int e=lane; e<n2; e+=64){
        int i = e/n, j = e - i*n;
        double ax=0.0, ay=0.0;
        for (int k=0;k<n;k++){
          cxd p = P[i*n+k], m = M[k*n+j];
          ax += p.x*m.x - p.y*m.y;
          ay += p.x*m.y + p.y*m.x;
        }
        T[e] = {ax*inv, ay*inv};
      }
    }
    __syncthreads();
    { cxd* tmp = P; P = T; T = tmp; }
    if (act){ for (int e=lane; e<n2; e+=64){ R[e].x += P[e].x; R[e].y += P[e].y; } }
    __syncthreads();
  }
  for (int s=0; s<10; ++s){
    if (act){
      for (int e=lane; e<n2; e+=64){
        int i = e/n, j = e - i*n;
        double ax=0.0, ay=0.0;
        for (int k=0;k<n;k++){
          cxd p = R[i*n+k], q = R[k*n+j];
          ax += p.x*q.x - p.y*q.y;
          ay += p.x*q.y + p.y*q.x;
        }
        T[e] = {ax, ay};
      }
    }
    __syncthreads();
    { cxd* tmp = R; R = T; T = tmp; }
    __syncthreads();
  }
}

// ------------- Kernel A: shared gate tables into d_ws (8 blocks) -----------
__global__ __launch_bounds__(256)
void gates_kernel(const float* __restrict__ dmag, const float* __restrict__ dphase,
                  const float* __restrict__ smag, const float* __restrict__ sphase,
                  float* __restrict__ wsf){
  __shared__ double lam[10];
  __shared__ double Vd[100];
  __shared__ double scr[4][4][200];     // [wave][buf] cxd[100]
  __shared__ double layres[16][200];    // S_lay (0..7), D_lay (8..15)
  const int tid = threadIdx.x;
  const int wv = tid >> 6, lane = tid & 63, g = blockIdx.x;
  float* ws_V  = wsf;
  float* ws_VT = wsf + 100;
  float* ws_W  = wsf + 200;
  cxf* ws_BS = (cxf*)(wsf + 1200);
  cxf* ws_UL = (cxf*)(wsf + 5000);

  if (tid < 10){
    double lo = -6.0, hi = 6.0;
    for (int it=0; it<80; ++it){
      double mid = 0.5*(lo+hi);
      int cnt = 0; double q = 1.0;
      for (int i=0;i<10;i++){
        q = -mid - (i ? (double)i/q : 0.0);
        if (fabs(q) < 1e-300) q = -1e-300;
        if (q < 0.0) cnt++;
      }
      if (cnt > tid) hi = mid; else lo = mid;
    }
    double x = 0.5*(lo+hi);
    double p[10];
    p[0] = 1.0; p[1] = x;
    for (int k=1;k<9;k++) p[k+1] = (x*p[k] - sqrt((double)k)*p[k-1]) * (1.0/sqrt((double)(k+1)));
    double nn=0.0; for (int k=0;k<10;k++) nn += p[k]*p[k];
    double inv = 1.0/sqrt(nn);
    lam[tid] = x;
    for (int k=0;k<10;k++){
      Vd[k*10+tid] = p[k]*inv;
      if (g == 0){
        ws_V[k*10+tid]  = (float)(p[k]*inv);
        ws_VT[tid*10+k] = (float)(p[k]*inv);
      }
    }
  }
  __syncthreads();

  const int nrounds = (g==7) ? 5 : 1;
  for (int r=0; r<nrounds; ++r){
    int t;
    if (g < 7) t = 4*g + wv;
    else       t = (r==0) ? ((wv==0) ? 28 : 64) : (29 + (r-1)*4 + wv);
    bool act = (t < 45);
    int n = 10, bn = 0, ilo = 0;
    if (act && t >= 10 && t < 29){
      bn = t - 10; ilo = bn < 10 ? 0 : bn - 9;
      int ihi = bn < 10 ? bn : 9;
      n = ihi - ilo + 1;
    }
    cxd* M = (cxd*)scr[wv][0];
    cxd* P = (cxd*)scr[wv][1];
    cxd* T = (cxd*)scr[wv][2];
    cxd* R = (cxd*)scr[wv][3];
    if (act){
      if (t < 10){
        double l = lam[t];   // Q = -0.5*(a - ad)
        for (int e=lane; e<100; e+=64){
          int i=e/10, j=e-10*i;
          double v = 0.0;
          if (j == i+1) v = -0.5*l*sqrt((double)(i+1));
          else if (i == j+1) v = 0.5*l*sqrt((double)i);
          M[e] = {v, 0.0};
        }
      } else if (t < 29){
        for (int e=lane; e<n*n; e+=64){
          int rr=e/n, c=e-n*rr;
          double v = 0.0;
          if (c == rr+1) v = THETA*sqrt((double)((ilo+rr+1)*(bn-ilo-rr)));
          else if (rr == c+1) v = THETA*sqrt((double)((ilo+c+1)*(bn-ilo-c)));
          M[e] = {0.0, v};
        }
      } else {
        int idx = t-29, kind = idx>>3, L=(idx>>2)&1, w=idx&3;
        double r_ = kind ? (double)dmag[L*4+w]   : (double)smag[L*4+w];
        double ph = kind ? (double)dphase[L*4+w] : (double)sphase[L*4+w];
        double zr = r_*cos(ph), zi = r_*sin(ph);
        for (int e=lane; e<100; e+=64){
          int i=e/10, j=e-10*i;
          M[e] = kind ? gen_disp(i,j,zr,zi) : gen_squeeze(i,j,zr,zi);
        }
      }
    }
    __syncthreads();
    expm_fixed(act, n, M, P, T, R, lane);
    if (act){
      if (t < 10){
        for (int e=lane;e<100;e+=64){
          int i=e/10, j=e-10*i;
          ws_W[t*100 + j*10 + i] = (float)R[e].x;   // transposed
        }
      } else if (t < 29){
        for (int e=lane;e<100;e+=64){
          int rr=e/10, c=e-10*rr;
          cxf o; o.x=0.f; o.y=0.f;
          if (rr < n && c < n){ o.x=(float)R[rr*n+c].x; o.y=(float)R[rr*n+c].y; }
          ws_BS[bn*100 + c*10 + rr]=o;              // zero-padded + transposed
        }
      } else {
        int idx = t-29;
        cxd* dst = (cxd*)layres[idx];
        for (int e=lane;e<100;e+=64) dst[e] = R[e];
      }
    }
    __syncthreads();
  }

  if (g == 7){
    for (int half=0; half<2; ++half){
      int f = wv + half*4;
      cxd* D  = (cxd*)layres[8+f];
      cxd* Sm = (cxd*)layres[f];
      cxd* prod = (cxd*)scr[wv][0];
      for (int e=lane;e<100;e+=64){
        int i=e/10, j=e-10*i;
        double ax=0, ay=0;
        for (int k=0;k<10;k++){
          cxd d=D[i*10+k], s=Sm[k*10+j];
          ax += d.x*s.x - d.y*s.y;
          ay += d.x*s.y + d.y*s.x;
        }
        prod[e] = {ax, ay};
      }
      __syncthreads();
      for (int e=lane;e<100;e+=64){
        int i=e/10, j=e-10*i;
        double ox, oy;
        if (f == 0){
          ox = 0; oy = 0;
          for (int k=0;k<10;k++){
            double v = Vd[k*10+i];
            ox += v*prod[k*10+j].x;
            oy += v*prod[k*10+j].y;
          }
        } else { ox = prod[e].x; oy = prod[e].y; }
        cxf o; o.x=(float)ox; o.y=(float)oy;
        ws_UL[f*100 + j*10 + i] = o;                // transposed
      }
      __syncthreads();
    }
  }
}

// ------------- Kernel B: per-(b,w) encoding vector u = D*(S*e0) ------------
__global__ __launch_bounds__(128)
void enc_kernel(const float* __restrict__ jets, const float* __restrict__ sscale,
                float* __restrict__ wsf){
  __shared__ double scr[2][4][200];
  __shared__ double col[20];
  __shared__ double uacc[20];
  const int tid = threadIdx.x, wv = tid>>6, lane = tid&63;
  const int blk = blockIdx.x, b = blk>>2, w = blk&3;

  double eta = (double)jets[b*12 + w*3 + 0];
  double jph = (double)jets[b*12 + w*3 + 1];
  double pt  = (double)jets[b*12 + w*3 + 2];

  cxd* M = (cxd*)scr[wv][0];
  cxd* P = (cxd*)scr[wv][1];
  cxd* T = (cxd*)scr[wv][2];
  cxd* R = (cxd*)scr[wv][3];
  {
    double zr, zi;
    if (wv == 0){ double phs = pt*jph*0.5; zr = eta*cos(phs); zi = eta*sin(phs); }
    else {
      double sc = 10.0/(1.0 + exp(-(double)sscale[0])) + 0.01;
      double mag = sc*pt; zr = mag*cos(eta); zi = mag*sin(eta);
    }
    for (int e=lane; e<100; e+=64){
      int i=e/10, j=e-10*i;
      M[e] = wv ? gen_disp(i,j,zr,zi) : gen_squeeze(i,j,zr,zi);
    }
  }
  __syncthreads();
  expm_fixed(true, 10, M, P, T, R, lane);
  cxd* Rs = (cxd*)scr[0][3];
  cxd* Rd = (cxd*)scr[1][3];
  if (tid < 10){ col[2*tid] = Rs[tid*10].x; col[2*tid+1] = Rs[tid*10].y; }
  __syncthreads();
  if (tid < 10){
    double ax=0, ay=0;
    for (int k=0;k<10;k++){
      cxd d = Rd[tid*10+k];
      double cr = col[2*k], ci = col[2*k+1];
      ax += d.x*cr - d.y*ci;
      ay += d.x*ci + d.y*cr;
    }
    uacc[2*tid] = ax; uacc[2*tid+1] = ay;
  }
  __syncthreads();
  if (tid < 10){
    double rx, ry;
    if (w == 0){
      rx = 0; ry = 0;
      for (int k=0;k<10;k++){
        double v = (double)wsf[k*10 + tid];
        rx += v*uacc[2*k];
        ry += v*uacc[2*k+1];
      }
    } else { rx = uacc[2*tid]; ry = uacc[2*tid+1]; }
    float* u_out = wsf + 6656 + (b*40 + w*10 + tid)*2;
    u_out[0] = (float)rx;
    u_out[1] = (float)ry;
  }
}

// ---------------- Kernel C: the circuit, state-only LDS --------------------
// Rolled-k gate bodies; 20 named scalar accumulators (never indexed).

#define DECL_ACC \
  float ox0=0.f,oy0=0.f, ox1=0.f,oy1=0.f, ox2=0.f,oy2=0.f, ox3=0.f,oy3=0.f, \
        ox4=0.f,oy4=0.f, ox5=0.f,oy5=0.f, ox6=0.f,oy6=0.f, ox7=0.f,oy7=0.f, \
        ox8=0.f,oy8=0.f, ox9=0.f,oy9=0.f;

#define CK(i)  { cxf u = U[kk+(i)];  ox##i += u.x*vx - u.y*vy; oy##i += u.x*vy + u.y*vx; }
#define RK(i)  { float u = Mt[kk+(i)]; ox##i += u*vx; oy##i += u*vy; }
#define BK(r)  { cxf u = Bt[kk+(r)]; ox##r += u.x*vx - u.y*vy; oy##r += u.x*vy + u.y*vx; }

#define FSTORE(i) { cxf o; o.x=ox##i; o.y=oy##i; S[base + (i)*sm] = o; }
#define ALLSTORE FSTORE(0) FSTORE(1) FSTORE(2) FSTORE(3) FSTORE(4) FSTORE(5) FSTORE(6) FSTORE(7) FSTORE(8) FSTORE(9)
#define BSTORE(r) if ((r) < sz){ int i=ilo+(r); cxf o; o.x=ox##r; o.y=oy##r; S[base + i*s1 + (bn-i)*s2] = o; }
#define BALLSTORE BSTORE(0) BSTORE(1) BSTORE(2) BSTORE(3) BSTORE(4) BSTORE(5) BSTORE(6) BSTORE(7) BSTORE(8) BSTORE(9)

// Single-mode complex gate (m may be runtime; strides wave-uniform).
__device__ __forceinline__ void apply1_c(cxf* S, const cxf* __restrict__ U, int m, int tid){
  const int sm = (m==0)?1000:((m==1)?100:((m==2)?10:1));
  const int r0 = (m==0)?1:0, r1=(m<=1)?2:1, r2=(m<=2)?3:2;
  const int s0 = (r0==0)?1000:((r0==1)?100:((r0==2)?10:1));
  const int s1 = (r1==0)?1000:((r1==1)?100:((r1==2)?10:1));
  const int s2 = (r2==0)?1000:((r2==1)?100:((r2==2)?10:1));
  int f = tid;
  if (f < 1000){
    int c0=f/100, rem=f-100*c0, c1=rem/10, c2=rem-10*c1;
    int base = c0*s0 + c1*s1 + c2*s2;
    DECL_ACC
    #pragma unroll 2
    for (int k=0;k<10;k++){
      cxf v = S[base + k*sm];
      float vx=v.x, vy=v.y;
      int kk = k*10;
      CK(0) CK(1) CK(2) CK(3) CK(4) CK(5) CK(6) CK(7) CK(8) CK(9)
    }
    ALLSTORE
  }
}

// Single-mode real gate. Pass ws_V for the V^T gate, ws_VT for V.
__device__ __forceinline__ void apply1_r(cxf* S, const float* __restrict__ Mt, int m, int tid){
  const int sm = (m==0)?1000:((m==1)?100:((m==2)?10:1));
  const int r0 = (m==0)?1:0, r1=(m<=1)?2:1, r2=(m<=2)?3:2;
  const int s0 = (r0==0)?1000:((r0==1)?100:((r0==2)?10:1));
  const int s1 = (r1==0)?1000:((r1==1)?100:((r1==2)?10:1));
  const int s2 = (r2==0)?1000:((r2==1)?100:((r2==2)?10:1));
  int f = tid;
  if (f < 1000){
    int c0=f/100, rem=f-100*c0, c1=rem/10, c2=rem-10*c1;
    int base = c0*s0 + c1*s1 + c2*s2;
    DECL_ACC
    #pragma unroll 2
    for (int k=0;k<10;k++){
      cxf v = S[base + k*sm];
      float vx=v.x, vy=v.y;
      int kk = k*10;
      RK(0) RK(1) RK(2) RK(3) RK(4) RK(5) RK(6) RK(7) RK(8) RK(9)
    }
    ALLSTORE
  }
}

// Conditional real gate on m2, W[n] selected by m1 digit (fiber MSD -> uniform n).
__device__ __forceinline__ void applyW(cxf* S, const float* __restrict__ Wall, int m1, int m2, int tid){
  const int sm  = (m2==0)?1000:((m2==1)?100:((m2==2)?10:1));
  const int sm1 = (m1==0)?1000:((m1==1)?100:((m1==2)?10:1));
  int ra=-1, rb=-1;
  for (int q=0;q<4;q++) if (q!=m1 && q!=m2){ if (ra<0) ra=q; else rb=q; }
  const int sa = (ra==0)?1000:((ra==1)?100:((ra==2)?10:1));
  const int sb = (rb==0)?1000:((rb==1)?100:((rb==2)?10:1));
  int f = tid;
  if (f < 1000){
    int n = f/100, rem = f-100*n, qa = rem/10, qb = rem-10*qa;
    int base = n*sm1 + qa*sa + qb*sb;
    const float* __restrict__ Mt = Wall + n*100;   // transposed W_n
    DECL_ACC
    #pragma unroll 2
    for (int k=0;k<10;k++){
      cxf v = S[base + k*sm];
      float vx=v.x, vy=v.y;
      int kk = k*10;
      RK(0) RK(1) RK(2) RK(3) RK(4) RK(5) RK(6) RK(7) RK(8) RK(9)
    }
    ALLSTORE
  }
}

// Beamsplitter via total-photon blocks, zero-padded transposed 10x10.
__device__ __forceinline__ void applyBS(cxf* S, const cxf* __restrict__ BSp, int m1, int m2, int tid){
  int ra=-1, rb=-1;
  for (int q=0;q<4;q++) if (q!=m1 && q!=m2){ if (ra<0) ra=q; else rb=q; }
  const int sa = (ra==0)?1000:((ra==1)?100:((ra==2)?10:1));
  const int sb = (rb==0)?1000:((rb==1)?100:((rb==2)?10:1));
  const int s1 = (m1==0)?1000:((m1==1)?100:((m1==2)?10:1));
  const int s2 = (m2==0)?1000:((m2==1)?100:((m2==2)?10:1));
  #pragma unroll 1
  for (int w0=0; w0<2048; w0+=NTB){
    int it = w0 + tid;
    if (it < 1900){
      int bn = it/100, rest = it-100*bn;
      int ilo = bn<10?0:bn-9, ihi = bn<10?bn:9, sz = ihi-ilo+1;
      int ca = rest/10, cb = rest-10*ca;
      int base = ca*sa + cb*sb;
      const cxf* __restrict__ Bt = BSp + bn*100;   // transposed, zero-padded
      DECL_ACC
      #pragma unroll 2
      for (int c=0;c<10;c++){
        int i = ilo + c;
        bool in = c < sz;
        cxf v = S[base + (in ? (i*s1 + (bn-i)*s2) : 0)];
        float vx = in ? v.x : 0.f, vy = in ? v.y : 0.f;
        int kk = c*10;
        BK(0) BK(1) BK(2) BK(3) BK(4) BK(5) BK(6) BK(7) BK(8) BK(9)
      }
      BALLSTORE
    }
  }
}

__global__ __launch_bounds__(NTB)
__attribute__((amdgpu_waves_per_eu(8)))
void state_kernel(const float* __restrict__ wd, const float* __restrict__ bd,
                  const float* __restrict__ wsf, float* __restrict__ out){
  extern __shared__ __align__(16) char smem[];
  cxf* S    = (cxf*)smem;                 // 10000 cxf (80000 B)
  cxf* uv   = (cxf*)(smem + 80000);       // 4*10 encoding vectors
  float* red = (float*)(smem + 80320);    // 16

  const float* __restrict__ V   = wsf;            // for V^T gate
  const float* __restrict__ VT  = wsf + 100;      // for V gate
  const float* __restrict__ W   = wsf + 200;
  const cxf*   __restrict__ BSm = (const cxf*)(wsf + 1200);
  const cxf*   __restrict__ UL  = (const cxf*)(wsf + 5000);
  const cxf*   __restrict__ uw  = (const cxf*)(wsf + 6656);

  const int tid = threadIdx.x, wv = tid>>6, lane = tid&63;
  const int b = blockIdx.x;

  if (tid < 40) uv[tid] = uw[b*40 + tid];
  __syncthreads();

  // Init: product state S = u0 (x) u1 (x) u2 (x) u3  (V0^T already folded in u0)
  for (int e=tid; e<10000; e+=NTB){
    int c0=e/1000, r_=e-1000*c0, c1=r_/100, r2_=r_-100*c1, c2=r2_/10, c3=r2_-10*c2;
    cxf A = uv[c0], B = uv[10+c1], C = uv[20+c2], D = uv[30+c3];
    float pr = A.x*B.x - A.y*B.y, pi = A.x*B.y + A.y*B.x;
    float qr = pr*C.x - pi*C.y,  qi = pr*C.y + pi*C.x;
    cxf o; o.x = qr*D.x - qi*D.y; o.y = qr*D.y + qi*D.x;
    S[e] = o;
  }
  __syncthreads();

  for (int L=0; L<2; ++L){
    // CX group a=0 (V0^T folded into u0 / UL[0]):
    applyW(S, W, 0, 1, tid); __syncthreads();
    applyW(S, W, 0, 2, tid); __syncthreads();
    applyW(S, W, 0, 3, tid); __syncthreads();
    apply1_r(S, VT, 0, tid); __syncthreads();      // V gate
    // a=1:
    apply1_r(S, V, 1, tid);  __syncthreads();      // V^T gate
    applyW(S, W, 1, 2, tid); __syncthreads();
    applyW(S, W, 1, 3, tid); __syncthreads();
    apply1_r(S, VT, 1, tid); __syncthreads();
    // a=2:
    apply1_r(S, V, 2, tid);  __syncthreads();
    applyW(S, W, 2, 3, tid); __syncthreads();
    apply1_r(S, VT, 2, tid); __syncthreads();
    // Beamsplitters:
    applyBS(S, BSm, 0, 1, tid); __syncthreads();
    applyBS(S, BSm, 1, 2, tid); __syncthreads();
    applyBS(S, BSm, 2, 3, tid); __syncthreads();
    applyBS(S, BSm, 3, 0, tid); __syncthreads();
    // Layer single-mode gates (UL[0] carries next layer's V0^T):
    for (int w=0; w<4; ++w){ apply1_c(S, UL + (L*4+w)*100, w, tid); __syncthreads(); }
  }

  float w0 = wd[0], w1 = wd[1], w2 = wd[2];
  float acc = 0.f;
  for (int e=tid; e<10000; e+=NTB){
    cxf z = S[e];
    float p = z.x*z.x + z.y*z.y;
    int n0 = e/1000, r_ = e-1000*n0, n1 = r_/100, r2_ = r_-100*n1, n2 = r2_/10;
    acc += p * ((float)n0*w0 + (float)n1*w1 + (float)n2*w2);
  }
  for (int off=32; off; off>>=1) acc += __shfl_down(acc, off, 64);
  if (lane == 0) red[wv] = acc;
  __syncthreads();
  if (tid == 0){
    float s = 0.f;
    for (int i=0;i<16;i++) s += red[i];
    out[b] = s + bd[0];
  }
}

} // anonymous namespace

extern "C" void kernel_launch(void* const* d_in, const int* in_sizes, int n_in,
                              void* d_out, int out_size, void* d_ws, size_t ws_size,
                              hipStream_t stream){
  const float* jets   = (const float*)d_in[0];
  const float* sscale = (const float*)d_in[1];
  const float* dmag   = (const float*)d_in[2];
  const float* dphase = (const float*)d_in[3];
  const float* smag   = (const float*)d_in[4];
  const float* sphase = (const float*)d_in[5];
  const float* wd     = (const float*)d_in[6];
  const float* bd     = (const float*)d_in[7];
  float* out = (float*)d_out;
  float* wsf = (float*)d_ws;
  int B = in_sizes[0] / 12;

  (void)hipFuncSetAttribute(reinterpret_cast<const void*>(&state_kernel),
                            hipFuncAttributeMaxDynamicSharedMemorySize, SMEM_BYTES);

  gates_kernel<<<8, 256, 0, stream>>>(dmag, dphase, smag, sphase, wsf);
  enc_kernel<<<B*4, 128, 0, stream>>>(jets, sscale, wsf);
  state_kernel<<<B, NTB, SMEM_BYTES, stream>>>(wd, bd, wsf, out);
}

// Round 8
// 1578.504 us; speedup vs baseline: 3.4881x; 1.1967x over previous
//
#include <hip/hip_runtime.h>
#include <math.h>

// CV-photonic circuit: WIRES=4, LAYERS=2, CUTOFF=10, BATCH=2048.
// R8 = R7 + ragged-c applyBS: runtime c-loop bound sz (removes the ~47%
// zero-padding FMA + per-c cndmask + wasted ds_reads), single-add address
// recurrence. Named scalar accumulators throughout (no allocas).

namespace {

constexpr int NTB = 1024;                // threads per state block (16 waves)
constexpr int SMEM_BYTES = 80384;        // state 80000 + uv 320 + red 64
constexpr double THETA = 0.7853981633974483096; // pi/4

struct cxf { float x, y; };
struct cxd { double x, y; };

// ws float layout (matrices stored TRANSPOSED for k-outer consumption):
// [0,100)      V    (V[k*10+m]; used directly for the V^T gate)
// [100,200)    VT   (VT[k*10+i] = V[i][k]; used for the V gate)
// [200,1200)   Wt   (10 real 10x10, per-n transposed: Wt[n*100+k*10+i]=W_n[i][k])
// [1200,5000)  BSt  cxf[19*100] zero-padded, transposed: BSt[bn*100+c*10+r]
// [5000,6600)  ULt  cxf[8*100] fused layer gates, transposed
// [6656,...)   u    cxf[B*4*10] encoded per-(b,w) vectors

__device__ __forceinline__ cxd gen_squeeze(int i, int j, double zr, double zi){
  if (j == i+2){ double g = 0.5*sqrt((double)((i+1)*(i+2))); return {zr*g, -zi*g}; }
  if (i == j+2){ double g = 0.5*sqrt((double)((j+1)*(j+2))); return {-zr*g, -zi*g}; }
  return {0.0, 0.0};
}
__device__ __forceinline__ cxd gen_disp(int i, int j, double ar, double ai){
  if (i == j+1){ double g = sqrt((double)i); return {ar*g, ai*g}; }
  if (j == i+1){ double g = sqrt((double)j); return {-ar*g, ai*g}; }
  return {0.0, 0.0};
}

// Wave-cooperative fixed-schedule expm: result = exp(M), n x n (n<=10).
__device__ void expm_fixed(bool act, int n, cxd* M, cxd* P, cxd* T, cxd* R, int lane){
  const int n2 = n*n;
  if (act){
    for (int e=lane; e<n2; e+=64){ M[e].x *= 0x1p-10; M[e].y *= 0x1p-10; }
    for (int e=lane; e<n2; e+=64){
      P[e] = M[e];
      cxd r = M[e];
      if (e % (n+1) == 0) r.x += 1.0;
      R[e] = r;
    }
  }
  __syncthreads();
  for (int t=2; t<=12; ++t){
    if (act){
      double inv = 1.0/(double)t;
      for (int e=lane; e<n2; e+=64){
        int i = e/n, j = e - i*n;
        double ax=0.0, ay=0.0;
        for (int k=0;k<n;k++){
          cxd p = P[i*n+k], m = M[k*n+j];
          ax += p.x*m.x - p.y*m.y;
          ay += p.x*m.y + p.y*m.x;
        }
        T[e] = {ax*inv, ay*inv};
      }
    }
    __syncthreads();
    { cxd* tmp = P; P = T; T = tmp; }
    if (act){ for (int e=lane; e<n2; e+=64){ R[e].x += P[e].x; R[e].y += P[e].y; } }
    __syncthreads();
  }
  for (int s=0; s<10; ++s){
    if (act){
      for (int e=lane; e<n2; e+=64){
        int i = e/n, j = e - i*n;
        double ax=0.0, ay=0.0;
        for (int k=0;k<n;k++){
          cxd p = R[i*n+k], q = R[k*n+j];
          ax += p.x*q.x - p.y*q.y;
          ay += p.x*q.y + p.y*q.x;
        }
        T[e] = {ax, ay};
      }
    }
    __syncthreads();
    { cxd* tmp = R; R = T; T = tmp; }
    __syncthreads();
  }
}

// ------------- Kernel A: shared gate tables into d_ws (8 blocks) -----------
__global__ __launch_bounds__(256)
void gates_kernel(const float* __restrict__ dmag, const float* __restrict__ dphase,
                  const float* __restrict__ smag, const float* __restrict__ sphase,
                  float* __restrict__ wsf){
  __shared__ double lam[10];
  __shared__ double Vd[100];
  __shared__ double scr[4][4][200];     // [wave][buf] cxd[100]
  __shared__ double layres[16][200];    // S_lay (0..7), D_lay (8..15)
  const int tid = threadIdx.x;
  const int wv = tid >> 6, lane = tid & 63, g = blockIdx.x;
  float* ws_V  = wsf;
  float* ws_VT = wsf + 100;
  float* ws_W  = wsf + 200;
  cxf* ws_BS = (cxf*)(wsf + 1200);
  cxf* ws_UL = (cxf*)(wsf + 5000);

  if (tid < 10){
    double lo = -6.0, hi = 6.0;
    for (int it=0; it<80; ++it){
      double mid = 0.5*(lo+hi);
      int cnt = 0; double q = 1.0;
      for (int i=0;i<10;i++){
        q = -mid - (i ? (double)i/q : 0.0);
        if (fabs(q) < 1e-300) q = -1e-300;
        if (q < 0.0) cnt++;
      }
      if (cnt > tid) hi = mid; else lo = mid;
    }
    double x = 0.5*(lo+hi);
    double p[10];
    p[0] = 1.0; p[1] = x;
    for (int k=1;k<9;k++) p[k+1] = (x*p[k] - sqrt((double)k)*p[k-1]) * (1.0/sqrt((double)(k+1)));
    double nn=0.0; for (int k=0;k<10;k++) nn += p[k]*p[k];
    double inv = 1.0/sqrt(nn);
    lam[tid] = x;
    for (int k=0;k<10;k++){
      Vd[k*10+tid] = p[k]*inv;
      if (g == 0){
        ws_V[k*10+tid]  = (float)(p[k]*inv);
        ws_VT[tid*10+k] = (float)(p[k]*inv);
      }
    }
  }
  __syncthreads();

  const int nrounds = (g==7) ? 5 : 1;
  for (int r=0; r<nrounds; ++r){
    int t;
    if (g < 7) t = 4*g + wv;
    else       t = (r==0) ? ((wv==0) ? 28 : 64) : (29 + (r-1)*4 + wv);
    bool act = (t < 45);
    int n = 10, bn = 0, ilo = 0;
    if (act && t >= 10 && t < 29){
      bn = t - 10; ilo = bn < 10 ? 0 : bn - 9;
      int ihi = bn < 10 ? bn : 9;
      n = ihi - ilo + 1;
    }
    cxd* M = (cxd*)scr[wv][0];
    cxd* P = (cxd*)scr[wv][1];
    cxd* T = (cxd*)scr[wv][2];
    cxd* R = (cxd*)scr[wv][3];
    if (act){
      if (t < 10){
        double l = lam[t];   // Q = -0.5*(a - ad)
        for (int e=lane; e<100; e+=64){
          int i=e/10, j=e-10*i;
          double v = 0.0;
          if (j == i+1) v = -0.5*l*sqrt((double)(i+1));
          else if (i == j+1) v = 0.5*l*sqrt((double)i);
          M[e] = {v, 0.0};
        }
      } else if (t < 29){
        for (int e=lane; e<n*n; e+=64){
          int rr=e/n, c=e-n*rr;
          double v = 0.0;
          if (c == rr+1) v = THETA*sqrt((double)((ilo+rr+1)*(bn-ilo-rr)));
          else if (rr == c+1) v = THETA*sqrt((double)((ilo+c+1)*(bn-ilo-c)));
          M[e] = {0.0, v};
        }
      } else {
        int idx = t-29, kind = idx>>3, L=(idx>>2)&1, w=idx&3;
        double r_ = kind ? (double)dmag[L*4+w]   : (double)smag[L*4+w];
        double ph = kind ? (double)dphase[L*4+w] : (double)sphase[L*4+w];
        double zr = r_*cos(ph), zi = r_*sin(ph);
        for (int e=lane; e<100; e+=64){
          int i=e/10, j=e-10*i;
          M[e] = kind ? gen_disp(i,j,zr,zi) : gen_squeeze(i,j,zr,zi);
        }
      }
    }
    __syncthreads();
    expm_fixed(act, n, M, P, T, R, lane);
    if (act){
      if (t < 10){
        for (int e=lane;e<100;e+=64){
          int i=e/10, j=e-10*i;
          ws_W[t*100 + j*10 + i] = (float)R[e].x;   // transposed
        }
      } else if (t < 29){
        for (int e=lane;e<100;e+=64){
          int rr=e/10, c=e-10*rr;
          cxf o; o.x=0.f; o.y=0.f;
          if (rr < n && c < n){ o.x=(float)R[rr*n+c].x; o.y=(float)R[rr*n+c].y; }
          ws_BS[bn*100 + c*10 + rr]=o;              // zero-padded + transposed
        }
      } else {
        int idx = t-29;
        cxd* dst = (cxd*)layres[idx];
        for (int e=lane;e<100;e+=64) dst[e] = R[e];
      }
    }
    __syncthreads();
  }

  if (g == 7){
    for (int half=0; half<2; ++half){
      int f = wv + half*4;
      cxd* D  = (cxd*)layres[8+f];
      cxd* Sm = (cxd*)layres[f];
      cxd* prod = (cxd*)scr[wv][0];
      for (int e=lane;e<100;e+=64){
        int i=e/10, j=e-10*i;
        double ax=0, ay=0;
        for (int k=0;k<10;k++){
          cxd d=D[i*10+k], s=Sm[k*10+j];
          ax += d.x*s.x - d.y*s.y;
          ay += d.x*s.y + d.y*s.x;
        }
        prod[e] = {ax, ay};
      }
      __syncthreads();
      for (int e=lane;e<100;e+=64){
        int i=e/10, j=e-10*i;
        double ox, oy;
        if (f == 0){
          ox = 0; oy = 0;
          for (int k=0;k<10;k++){
            double v = Vd[k*10+i];
            ox += v*prod[k*10+j].x;
            oy += v*prod[k*10+j].y;
          }
        } else { ox = prod[e].x; oy = prod[e].y; }
        cxf o; o.x=(float)ox; o.y=(float)oy;
        ws_UL[f*100 + j*10 + i] = o;                // transposed
      }
      __syncthreads();
    }
  }
}

// ------------- Kernel B: per-(b,w) encoding vector u = D*(S*e0) ------------
__global__ __launch_bounds__(128)
void enc_kernel(const float* __restrict__ jets, const float* __restrict__ sscale,
                float* __restrict__ wsf){
  __shared__ double scr[2][4][200];
  __shared__ double col[20];
  __shared__ double uacc[20];
  const int tid = threadIdx.x, wv = tid>>6, lane = tid&63;
  const int blk = blockIdx.x, b = blk>>2, w = blk&3;

  double eta = (double)jets[b*12 + w*3 + 0];
  double jph = (double)jets[b*12 + w*3 + 1];
  double pt  = (double)jets[b*12 + w*3 + 2];

  cxd* M = (cxd*)scr[wv][0];
  cxd* P = (cxd*)scr[wv][1];
  cxd* T = (cxd*)scr[wv][2];
  cxd* R = (cxd*)scr[wv][3];
  {
    double zr, zi;
    if (wv == 0){ double phs = pt*jph*0.5; zr = eta*cos(phs); zi = eta*sin(phs); }
    else {
      double sc = 10.0/(1.0 + exp(-(double)sscale[0])) + 0.01;
      double mag = sc*pt; zr = mag*cos(eta); zi = mag*sin(eta);
    }
    for (int e=lane; e<100; e+=64){
      int i=e/10, j=e-10*i;
      M[e] = wv ? gen_disp(i,j,zr,zi) : gen_squeeze(i,j,zr,zi);
    }
  }
  __syncthreads();
  expm_fixed(true, 10, M, P, T, R, lane);
  cxd* Rs = (cxd*)scr[0][3];
  cxd* Rd = (cxd*)scr[1][3];
  if (tid < 10){ col[2*tid] = Rs[tid*10].x; col[2*tid+1] = Rs[tid*10].y; }
  __syncthreads();
  if (tid < 10){
    double ax=0, ay=0;
    for (int k=0;k<10;k++){
      cxd d = Rd[tid*10+k];
      double cr = col[2*k], ci = col[2*k+1];
      ax += d.x*cr - d.y*ci;
      ay += d.x*ci + d.y*cr;
    }
    uacc[2*tid] = ax; uacc[2*tid+1] = ay;
  }
  __syncthreads();
  if (tid < 10){
    double rx, ry;
    if (w == 0){
      rx = 0; ry = 0;
      for (int k=0;k<10;k++){
        double v = (double)wsf[k*10 + tid];
        rx += v*uacc[2*k];
        ry += v*uacc[2*k+1];
      }
    } else { rx = uacc[2*tid]; ry = uacc[2*tid+1]; }
    float* u_out = wsf + 6656 + (b*40 + w*10 + tid)*2;
    u_out[0] = (float)rx;
    u_out[1] = (float)ry;
  }
}

// ---------------- Kernel C: the circuit, state-only LDS --------------------
// Rolled-k gate bodies; 20 named scalar accumulators (never indexed).

#define DECL_ACC \
  float ox0=0.f,oy0=0.f, ox1=0.f,oy1=0.f, ox2=0.f,oy2=0.f, ox3=0.f,oy3=0.f, \
        ox4=0.f,oy4=0.f, ox5=0.f,oy5=0.f, ox6=0.f,oy6=0.f, ox7=0.f,oy7=0.f, \
        ox8=0.f,oy8=0.f, ox9=0.f,oy9=0.f;

#define CK(i)  { cxf u = U[kk+(i)];  ox##i += u.x*vx - u.y*vy; oy##i += u.x*vy + u.y*vx; }
#define RK(i)  { float u = Mt[kk+(i)]; ox##i += u*vx; oy##i += u*vy; }
#define BK(r)  { cxf u = Bt[kk+(r)]; ox##r += u.x*vx - u.y*vy; oy##r += u.x*vy + u.y*vx; }

#define FSTORE(i) { cxf o; o.x=ox##i; o.y=oy##i; S[base + (i)*sm] = o; }
#define ALLSTORE FSTORE(0) FSTORE(1) FSTORE(2) FSTORE(3) FSTORE(4) FSTORE(5) FSTORE(6) FSTORE(7) FSTORE(8) FSTORE(9)
#define BSTORE(r) if ((r) < sz){ cxf o; o.x=ox##r; o.y=oy##r; S[wadr] = o; wadr += ds; }
#define BALLSTORE BSTORE(0) BSTORE(1) BSTORE(2) BSTORE(3) BSTORE(4) BSTORE(5) BSTORE(6) BSTORE(7) BSTORE(8) BSTORE(9)

// Single-mode complex gate (m compile-time after inlining).
__device__ __forceinline__ void apply1_c(cxf* S, const cxf* __restrict__ U, int m, int tid){
  const int sm = (m==0)?1000:((m==1)?100:((m==2)?10:1));
  const int r0 = (m==0)?1:0, r1=(m<=1)?2:1, r2=(m<=2)?3:2;
  const int s0 = (r0==0)?1000:((r0==1)?100:((r0==2)?10:1));
  const int s1 = (r1==0)?1000:((r1==1)?100:((r1==2)?10:1));
  const int s2 = (r2==0)?1000:((r2==1)?100:((r2==2)?10:1));
  int f = tid;
  if (f < 1000){
    int c0=f/100, rem=f-100*c0, c1=rem/10, c2=rem-10*c1;
    int base = c0*s0 + c1*s1 + c2*s2;
    DECL_ACC
    #pragma unroll 2
    for (int k=0;k<10;k++){
      cxf v = S[base + k*sm];
      float vx=v.x, vy=v.y;
      int kk = k*10;
      CK(0) CK(1) CK(2) CK(3) CK(4) CK(5) CK(6) CK(7) CK(8) CK(9)
    }
    ALLSTORE
  }
}

// Single-mode real gate. Pass ws_V for the V^T gate, ws_VT for V.
__device__ __forceinline__ void apply1_r(cxf* S, const float* __restrict__ Mt, int m, int tid){
  const int sm = (m==0)?1000:((m==1)?100:((m==2)?10:1));
  const int r0 = (m==0)?1:0, r1=(m<=1)?2:1, r2=(m<=2)?3:2;
  const int s0 = (r0==0)?1000:((r0==1)?100:((r0==2)?10:1));
  const int s1 = (r1==0)?1000:((r1==1)?100:((r1==2)?10:1));
  const int s2 = (r2==0)?1000:((r2==1)?100:((r2==2)?10:1));
  int f = tid;
  if (f < 1000){
    int c0=f/100, rem=f-100*c0, c1=rem/10, c2=rem-10*c1;
    int base = c0*s0 + c1*s1 + c2*s2;
    DECL_ACC
    #pragma unroll 2
    for (int k=0;k<10;k++){
      cxf v = S[base + k*sm];
      float vx=v.x, vy=v.y;
      int kk = k*10;
      RK(0) RK(1) RK(2) RK(3) RK(4) RK(5) RK(6) RK(7) RK(8) RK(9)
    }
    ALLSTORE
  }
}

// Conditional real gate on m2, W[n] selected by m1 digit (fiber MSD -> uniform n).
__device__ __forceinline__ void applyW(cxf* S, const float* __restrict__ Wall, int m1, int m2, int tid){
  const int sm  = (m2==0)?1000:((m2==1)?100:((m2==2)?10:1));
  const int sm1 = (m1==0)?1000:((m1==1)?100:((m1==2)?10:1));
  int ra=-1, rb=-1;
  for (int q=0;q<4;q++) if (q!=m1 && q!=m2){ if (ra<0) ra=q; else rb=q; }
  const int sa = (ra==0)?1000:((ra==1)?100:((ra==2)?10:1));
  const int sb = (rb==0)?1000:((rb==1)?100:((rb==2)?10:1));
  int f = tid;
  if (f < 1000){
    int n = f/100, rem = f-100*n, qa = rem/10, qb = rem-10*qa;
    int base = n*sm1 + qa*sa + qb*sb;
    const float* __restrict__ Mt = Wall + n*100;   // transposed W_n
    DECL_ACC
    #pragma unroll 2
    for (int k=0;k<10;k++){
      cxf v = S[base + k*sm];
      float vx=v.x, vy=v.y;
      int kk = k*10;
      RK(0) RK(1) RK(2) RK(3) RK(4) RK(5) RK(6) RK(7) RK(8) RK(9)
    }
    ALLSTORE
  }
}

// Beamsplitter via total-photon blocks; RAGGED c-loop (bound sz at runtime),
// address recurrence addr += (s1 - s2). r-direction stays scalar-unrolled.
__device__ __forceinline__ void applyBS(cxf* S, const cxf* __restrict__ BSp, int m1, int m2, int tid){
  int ra=-1, rb=-1;
  for (int q=0;q<4;q++) if (q!=m1 && q!=m2){ if (ra<0) ra=q; else rb=q; }
  const int sa = (ra==0)?1000:((ra==1)?100:((ra==2)?10:1));
  const int sb = (rb==0)?1000:((rb==1)?100:((rb==2)?10:1));
  const int s1 = (m1==0)?1000:((m1==1)?100:((m1==2)?10:1));
  const int s2 = (m2==0)?1000:((m2==1)?100:((m2==2)?10:1));
  const int ds = s1 - s2;
  #pragma unroll 1
  for (int w0=0; w0<2048; w0+=NTB){
    int it = w0 + tid;
    if (it < 1900){
      int bn = it/100, rest = it-100*bn;
      int ilo = bn<10?0:bn-9, ihi = bn<10?bn:9, sz = ihi-ilo+1;
      int ca = rest/10, cb = rest-10*ca;
      int base = ca*sa + cb*sb;
      const cxf* __restrict__ Bt = BSp + bn*100;   // transposed (zero-pad unused)
      DECL_ACC
      int radr = base + ilo*s1 + (bn-ilo)*s2;      // element (ilo+c, bn-ilo-c)
      int kk = 0;
      #pragma unroll 1
      for (int c=0;c<sz;c++){
        cxf v = S[radr];
        float vx=v.x, vy=v.y;
        BK(0) BK(1) BK(2) BK(3) BK(4) BK(5) BK(6) BK(7) BK(8) BK(9)
        radr += ds; kk += 10;
      }
      int wadr = base + ilo*s1 + (bn-ilo)*s2;
      BALLSTORE
    }
  }
}

__global__ __launch_bounds__(NTB)
__attribute__((amdgpu_waves_per_eu(8)))
void state_kernel(const float* __restrict__ wd, const float* __restrict__ bd,
                  const float* __restrict__ wsf, float* __restrict__ out){
  extern __shared__ __align__(16) char smem[];
  cxf* S    = (cxf*)smem;                 // 10000 cxf (80000 B)
  cxf* uv   = (cxf*)(smem + 80000);       // 4*10 encoding vectors
  float* red = (float*)(smem + 80320);    // 16

  const float* __restrict__ V   = wsf;            // for V^T gate
  const float* __restrict__ VT  = wsf + 100;      // for V gate
  const float* __restrict__ W   = wsf + 200;
  const cxf*   __restrict__ BSm = (const cxf*)(wsf + 1200);
  const cxf*   __restrict__ UL  = (const cxf*)(wsf + 5000);
  const cxf*   __restrict__ uw  = (const cxf*)(wsf + 6656);

  const int tid = threadIdx.x, wv = tid>>6, lane = tid&63;
  const int b = blockIdx.x;

  if (tid < 40) uv[tid] = uw[b*40 + tid];
  __syncthreads();

  // Init: product state S = u0 (x) u1 (x) u2 (x) u3  (V0^T already folded in u0)
  for (int e=tid; e<10000; e+=NTB){
    int c0=e/1000, r_=e-1000*c0, c1=r_/100, r2_=r_-100*c1, c2=r2_/10, c3=r2_-10*c2;
    cxf A = uv[c0], B = uv[10+c1], C = uv[20+c2], D = uv[30+c3];
    float pr = A.x*B.x - A.y*B.y, pi = A.x*B.y + A.y*B.x;
    float qr = pr*C.x - pi*C.y,  qi = pr*C.y + pi*C.x;
    cxf o; o.x = qr*D.x - qi*D.y; o.y = qr*D.y + qi*D.x;
    S[e] = o;
  }
  __syncthreads();

  for (int L=0; L<2; ++L){
    // CX group a=0 (V0^T folded into u0 / UL[0]):
    applyW(S, W, 0, 1, tid); __syncthreads();
    applyW(S, W, 0, 2, tid); __syncthreads();
    applyW(S, W, 0, 3, tid); __syncthreads();
    apply1_r(S, VT, 0, tid); __syncthreads();      // V gate
    // a=1:
    apply1_r(S, V, 1, tid);  __syncthreads();      // V^T gate
    applyW(S, W, 1, 2, tid); __syncthreads();
    applyW(S, W, 1, 3, tid); __syncthreads();
    apply1_r(S, VT, 1, tid); __syncthreads();
    // a=2:
    apply1_r(S, V, 2, tid);  __syncthreads();
    applyW(S, W, 2, 3, tid); __syncthreads();
    apply1_r(S, VT, 2, tid); __syncthreads();
    // Beamsplitters:
    applyBS(S, BSm, 0, 1, tid); __syncthreads();
    applyBS(S, BSm, 1, 2, tid); __syncthreads();
    applyBS(S, BSm, 2, 3, tid); __syncthreads();
    applyBS(S, BSm, 3, 0, tid); __syncthreads();
    // Layer single-mode gates (UL[0] carries next layer's V0^T):
    for (int w=0; w<4; ++w){ apply1_c(S, UL + (L*4+w)*100, w, tid); __syncthreads(); }
  }

  float w0 = wd[0], w1 = wd[1], w2 = wd[2];
  float acc = 0.f;
  for (int e=tid; e<10000; e+=NTB){
    cxf z = S[e];
    float p = z.x*z.x + z.y*z.y;
    int n0 = e/1000, r_ = e-1000*n0, n1 = r_/100, r2_ = r_-100*n1, n2 = r2_/10;
    acc += p * ((float)n0*w0 + (float)n1*w1 + (float)n2*w2);
  }
  for (int off=32; off; off>>=1) acc += __shfl_down(acc, off, 64);
  if (lane == 0) red[wv] = acc;
  __syncthreads();
  if (tid == 0){
    float s = 0.f;
    for (int i=0;i<16;i++) s += red[i];
    out[b] = s + bd[0];
  }
}

} // anonymous namespace

extern "C" void kernel_launch(void* const* d_in, const int* in_sizes, int n_in,
                              void* d_out, int out_size, void* d_ws, size_t ws_size,
                              hipStream_t stream){
  const float* jets   = (const float*)d_in[0];
  const float* sscale = (const float*)d_in[1];
  const float* dmag   = (const float*)d_in[2];
  const float* dphase = (const float*)d_in[3];
  const float* smag   = (const float*)d_in[4];
  const float* sphase = (const float*)d_in[5];
  const float* wd     = (const float*)d_in[6];
  const float* bd     = (const float*)d_in[7];
  float* out = (float*)d_out;
  float* wsf = (float*)d_ws;
  int B = in_sizes[0] / 12;

  (void)hipFuncSetAttribute(reinterpret_cast<const void*>(&state_kernel),
                            hipFuncAttributeMaxDynamicSharedMemorySize, SMEM_BYTES);

  gates_kernel<<<8, 256, 0, stream>>>(dmag, dphase, smag, sphase, wsf);
  enc_kernel<<<B*4, 128, 0, stream>>>(jets, sscale, wsf);
  state_kernel<<<B, NTB, SMEM_BYTES, stream>>>(wd, bd, wsf, out);
}

// Round 9
// 1344.308 us; speedup vs baseline: 4.0958x; 1.1742x over previous
//
#include <hip/hip_runtime.h>
#include <math.h>

// CV-photonic circuit: WIRES=4, LAYERS=2, CUTOFF=10, BATCH=2048.
// R9 = R8 + packed dual-FP32 math: gate bodies use v2f accumulators and
// __builtin_elementwise_fma so (ox,oy) updates become v_pk_fma_f32
// (real: 1 instr/(i,k) vs 2; complex: 2 vs 3-6). Explicit reassociation
// (fma chains) is within the 3.6e-2 tolerance. Still no local arrays.

namespace {

constexpr int NTB = 1024;                // threads per state block (16 waves)
constexpr int SMEM_BYTES = 80384;        // state 80000 + uv 320 + red 64
constexpr double THETA = 0.7853981633974483096; // pi/4

struct cxf { float x, y; };
struct cxd { double x, y; };
typedef float v2f __attribute__((ext_vector_type(2)));

// ws float layout (matrices stored TRANSPOSED for k-outer consumption):
// [0,100)      V    (V[k*10+m]; used directly for the V^T gate)
// [100,200)    VT   (VT[k*10+i] = V[i][k]; used for the V gate)
// [200,1200)   Wt   (10 real 10x10, per-n transposed: Wt[n*100+k*10+i]=W_n[i][k])
// [1200,5000)  BSt  cxf[19*100] zero-padded, transposed: BSt[bn*100+c*10+r]
// [5000,6600)  ULt  cxf[8*100] fused layer gates, transposed
// [6656,...)   u    cxf[B*4*10] encoded per-(b,w) vectors

__device__ __forceinline__ cxd gen_squeeze(int i, int j, double zr, double zi){
  if (j == i+2){ double g = 0.5*sqrt((double)((i+1)*(i+2))); return {zr*g, -zi*g}; }
  if (i == j+2){ double g = 0.5*sqrt((double)((j+1)*(j+2))); return {-zr*g, -zi*g}; }
  return {0.0, 0.0};
}
__device__ __forceinline__ cxd gen_disp(int i, int j, double ar, double ai){
  if (i == j+1){ double g = sqrt((double)i); return {ar*g, ai*g}; }
  if (j == i+1){ double g = sqrt((double)j); return {-ar*g, ai*g}; }
  return {0.0, 0.0};
}

// Wave-cooperative fixed-schedule expm: result = exp(M), n x n (n<=10).
__device__ void expm_fixed(bool act, int n, cxd* M, cxd* P, cxd* T, cxd* R, int lane){
  const int n2 = n*n;
  if (act){
    for (int e=lane; e<n2; e+=64){ M[e].x *= 0x1p-10; M[e].y *= 0x1p-10; }
    for (int e=lane; e<n2; e+=64){
      P[e] = M[e];
      cxd r = M[e];
      if (e % (n+1) == 0) r.x += 1.0;
      R[e] = r;
    }
  }
  __syncthreads();
  for (int t=2; t<=12; ++t){
    if (act){
      double inv = 1.0/(double)t;
      for (int e=lane; e<n2; e+=64){
        int i = e/n, j = e - i*n;
        double ax=0.0, ay=0.0;
        for (int k=0;k<n;k++){
          cxd p = P[i*n+k], m = M[k*n+j];
          ax += p.x*m.x - p.y*m.y;
          ay += p.x*m.y + p.y*m.x;
        }
        T[e] = {ax*inv, ay*inv};
      }
    }
    __syncthreads();
    { cxd* tmp = P; P = T; T = tmp; }
    if (act){ for (int e=lane; e<n2; e+=64){ R[e].x += P[e].x; R[e].y += P[e].y; } }
    __syncthreads();
  }
  for (int s=0; s<10; ++s){
    if (act){
      for (int e=lane; e<n2; e+=64){
        int i = e/n, j = e - i*n;
        double ax=0.0, ay=0.0;
        for (int k=0;k<n;k++){
          cxd p = R[i*n+k], q = R[k*n+j];
          ax += p.x*q.x - p.y*q.y;
          ay += p.x*q.y + p.y*q.x;
        }
        T[e] = {ax, ay};
      }
    }
    __syncthreads();
    { cxd* tmp = R; R = T; T = tmp; }
    __syncthreads();
  }
}

// ------------- Kernel A: shared gate tables into d_ws (8 blocks) -----------
__global__ __launch_bounds__(256)
void gates_kernel(const float* __restrict__ dmag, const float* __restrict__ dphase,
                  const float* __restrict__ smag, const float* __restrict__ sphase,
                  float* __restrict__ wsf){
  __shared__ double lam[10];
  __shared__ double Vd[100];
  __shared__ double scr[4][4][200];     // [wave][buf] cxd[100]
  __shared__ double layres[16][200];    // S_lay (0..7), D_lay (8..15)
  const int tid = threadIdx.x;
  const int wv = tid >> 6, lane = tid & 63, g = blockIdx.x;
  float* ws_V  = wsf;
  float* ws_VT = wsf + 100;
  float* ws_W  = wsf + 200;
  cxf* ws_BS = (cxf*)(wsf + 1200);
  cxf* ws_UL = (cxf*)(wsf + 5000);

  if (tid < 10){
    double lo = -6.0, hi = 6.0;
    for (int it=0; it<80; ++it){
      double mid = 0.5*(lo+hi);
      int cnt = 0; double q = 1.0;
      for (int i=0;i<10;i++){
        q = -mid - (i ? (double)i/q : 0.0);
        if (fabs(q) < 1e-300) q = -1e-300;
        if (q < 0.0) cnt++;
      }
      if (cnt > tid) hi = mid; else lo = mid;
    }
    double x = 0.5*(lo+hi);
    double p[10];
    p[0] = 1.0; p[1] = x;
    for (int k=1;k<9;k++) p[k+1] = (x*p[k] - sqrt((double)k)*p[k-1]) * (1.0/sqrt((double)(k+1)));
    double nn=0.0; for (int k=0;k<10;k++) nn += p[k]*p[k];
    double inv = 1.0/sqrt(nn);
    lam[tid] = x;
    for (int k=0;k<10;k++){
      Vd[k*10+tid] = p[k]*inv;
      if (g == 0){
        ws_V[k*10+tid]  = (float)(p[k]*inv);
        ws_VT[tid*10+k] = (float)(p[k]*inv);
      }
    }
  }
  __syncthreads();

  const int nrounds = (g==7) ? 5 : 1;
  for (int r=0; r<nrounds; ++r){
    int t;
    if (g < 7) t = 4*g + wv;
    else       t = (r==0) ? ((wv==0) ? 28 : 64) : (29 + (r-1)*4 + wv);
    bool act = (t < 45);
    int n = 10, bn = 0, ilo = 0;
    if (act && t >= 10 && t < 29){
      bn = t - 10; ilo = bn < 10 ? 0 : bn - 9;
      int ihi = bn < 10 ? bn : 9;
      n = ihi - ilo + 1;
    }
    cxd* M = (cxd*)scr[wv][0];
    cxd* P = (cxd*)scr[wv][1];
    cxd* T = (cxd*)scr[wv][2];
    cxd* R = (cxd*)scr[wv][3];
    if (act){
      if (t < 10){
        double l = lam[t];   // Q = -0.5*(a - ad)
        for (int e=lane; e<100; e+=64){
          int i=e/10, j=e-10*i;
          double v = 0.0;
          if (j == i+1) v = -0.5*l*sqrt((double)(i+1));
          else if (i == j+1) v = 0.5*l*sqrt((double)i);
          M[e] = {v, 0.0};
        }
      } else if (t < 29){
        for (int e=lane; e<n*n; e+=64){
          int rr=e/n, c=e-n*rr;
          double v = 0.0;
          if (c == rr+1) v = THETA*sqrt((double)((ilo+rr+1)*(bn-ilo-rr)));
          else if (rr == c+1) v = THETA*sqrt((double)((ilo+c+1)*(bn-ilo-c)));
          M[e] = {0.0, v};
        }
      } else {
        int idx = t-29, kind = idx>>3, L=(idx>>2)&1, w=idx&3;
        double r_ = kind ? (double)dmag[L*4+w]   : (double)smag[L*4+w];
        double ph = kind ? (double)dphase[L*4+w] : (double)sphase[L*4+w];
        double zr = r_*cos(ph), zi = r_*sin(ph);
        for (int e=lane; e<100; e+=64){
          int i=e/10, j=e-10*i;
          M[e] = kind ? gen_disp(i,j,zr,zi) : gen_squeeze(i,j,zr,zi);
        }
      }
    }
    __syncthreads();
    expm_fixed(act, n, M, P, T, R, lane);
    if (act){
      if (t < 10){
        for (int e=lane;e<100;e+=64){
          int i=e/10, j=e-10*i;
          ws_W[t*100 + j*10 + i] = (float)R[e].x;   // transposed
        }
      } else if (t < 29){
        for (int e=lane;e<100;e+=64){
          int rr=e/10, c=e-10*rr;
          cxf o; o.x=0.f; o.y=0.f;
          if (rr < n && c < n){ o.x=(float)R[rr*n+c].x; o.y=(float)R[rr*n+c].y; }
          ws_BS[bn*100 + c*10 + rr]=o;              // zero-padded + transposed
        }
      } else {
        int idx = t-29;
        cxd* dst = (cxd*)layres[idx];
        for (int e=lane;e<100;e+=64) dst[e] = R[e];
      }
    }
    __syncthreads();
  }

  if (g == 7){
    for (int half=0; half<2; ++half){
      int f = wv + half*4;
      cxd* D  = (cxd*)layres[8+f];
      cxd* Sm = (cxd*)layres[f];
      cxd* prod = (cxd*)scr[wv][0];
      for (int e=lane;e<100;e+=64){
        int i=e/10, j=e-10*i;
        double ax=0, ay=0;
        for (int k=0;k<10;k++){
          cxd d=D[i*10+k], s=Sm[k*10+j];
          ax += d.x*s.x - d.y*s.y;
          ay += d.x*s.y + d.y*s.x;
        }
        prod[e] = {ax, ay};
      }
      __syncthreads();
      for (int e=lane;e<100;e+=64){
        int i=e/10, j=e-10*i;
        double ox, oy;
        if (f == 0){
          ox = 0; oy = 0;
          for (int k=0;k<10;k++){
            double v = Vd[k*10+i];
            ox += v*prod[k*10+j].x;
            oy += v*prod[k*10+j].y;
          }
        } else { ox = prod[e].x; oy = prod[e].y; }
        cxf o; o.x=(float)ox; o.y=(float)oy;
        ws_UL[f*100 + j*10 + i] = o;                // transposed
      }
      __syncthreads();
    }
  }
}

// ------------- Kernel B: per-(b,w) encoding vector u = D*(S*e0) ------------
__global__ __launch_bounds__(128)
void enc_kernel(const float* __restrict__ jets, const float* __restrict__ sscale,
                float* __restrict__ wsf){
  __shared__ double scr[2][4][200];
  __shared__ double col[20];
  __shared__ double uacc[20];
  const int tid = threadIdx.x, wv = tid>>6, lane = tid&63;
  const int blk = blockIdx.x, b = blk>>2, w = blk&3;

  double eta = (double)jets[b*12 + w*3 + 0];
  double jph = (double)jets[b*12 + w*3 + 1];
  double pt  = (double)jets[b*12 + w*3 + 2];

  cxd* M = (cxd*)scr[wv][0];
  cxd* P = (cxd*)scr[wv][1];
  cxd* T = (cxd*)scr[wv][2];
  cxd* R = (cxd*)scr[wv][3];
  {
    double zr, zi;
    if (wv == 0){ double phs = pt*jph*0.5; zr = eta*cos(phs); zi = eta*sin(phs); }
    else {
      double sc = 10.0/(1.0 + exp(-(double)sscale[0])) + 0.01;
      double mag = sc*pt; zr = mag*cos(eta); zi = mag*sin(eta);
    }
    for (int e=lane; e<100; e+=64){
      int i=e/10, j=e-10*i;
      M[e] = wv ? gen_disp(i,j,zr,zi) : gen_squeeze(i,j,zr,zi);
    }
  }
  __syncthreads();
  expm_fixed(true, 10, M, P, T, R, lane);
  cxd* Rs = (cxd*)scr[0][3];
  cxd* Rd = (cxd*)scr[1][3];
  if (tid < 10){ col[2*tid] = Rs[tid*10].x; col[2*tid+1] = Rs[tid*10].y; }
  __syncthreads();
  if (tid < 10){
    double ax=0, ay=0;
    for (int k=0;k<10;k++){
      cxd d = Rd[tid*10+k];
      double cr = col[2*k], ci = col[2*k+1];
      ax += d.x*cr - d.y*ci;
      ay += d.x*ci + d.y*cr;
    }
    uacc[2*tid] = ax; uacc[2*tid+1] = ay;
  }
  __syncthreads();
  if (tid < 10){
    double rx, ry;
    if (w == 0){
      rx = 0; ry = 0;
      for (int k=0;k<10;k++){
        double v = (double)wsf[k*10 + tid];
        rx += v*uacc[2*k];
        ry += v*uacc[2*k+1];
      }
    } else { rx = uacc[2*tid]; ry = uacc[2*tid+1]; }
    float* u_out = wsf + 6656 + (b*40 + w*10 + tid)*2;
    u_out[0] = (float)rx;
    u_out[1] = (float)ry;
  }
}

// ---------------- Kernel C: the circuit, state-only LDS --------------------
// Packed v2f accumulators (named, never indexed) + elementwise fma ->
// v_pk_fma_f32. Real (i,k): 1 pk-fma; complex (i,k): 2 pk-fma.

#define DECL_ACCP \
  v2f a0={0.f,0.f}, a1={0.f,0.f}, a2={0.f,0.f}, a3={0.f,0.f}, a4={0.f,0.f}, \
      a5={0.f,0.f}, a6={0.f,0.f}, a7={0.f,0.f}, a8={0.f,0.f}, a9={0.f,0.f};

// complex: acc_i += u * v  (complex mul), u from table (cxf pair)
#define CKP(i) { v2f u = *(const v2f*)&U[kk+(i)]; \
  a##i = __builtin_elementwise_fma((v2f){u.x,u.x}, vv, a##i); \
  a##i = __builtin_elementwise_fma((v2f){-u.y,u.y}, vs, a##i); }
// real: acc_i += u * v (scalar times complex)
#define RKP(i) { float u = Mt[kk+(i)]; \
  a##i = __builtin_elementwise_fma((v2f){u,u}, vv, a##i); }
// BS complex, table Bt
#define BKP(r) { v2f u = *(const v2f*)&Bt[kk+(r)]; \
  a##r = __builtin_elementwise_fma((v2f){u.x,u.x}, vv, a##r); \
  a##r = __builtin_elementwise_fma((v2f){-u.y,u.y}, vs, a##r); }

#define PSTORE(i) { *(v2f*)&S[base + (i)*sm] = a##i; }
#define PALLSTORE PSTORE(0) PSTORE(1) PSTORE(2) PSTORE(3) PSTORE(4) PSTORE(5) PSTORE(6) PSTORE(7) PSTORE(8) PSTORE(9)
#define BPSTORE(r) if ((r) < sz){ *(v2f*)&S[wadr] = a##r; wadr += ds; }
#define BPALLSTORE BPSTORE(0) BPSTORE(1) BPSTORE(2) BPSTORE(3) BPSTORE(4) BPSTORE(5) BPSTORE(6) BPSTORE(7) BPSTORE(8) BPSTORE(9)

// Single-mode complex gate (m compile-time after inlining).
__device__ __forceinline__ void apply1_c(cxf* S, const cxf* __restrict__ U, int m, int tid){
  const int sm = (m==0)?1000:((m==1)?100:((m==2)?10:1));
  const int r0 = (m==0)?1:0, r1=(m<=1)?2:1, r2=(m<=2)?3:2;
  const int s0 = (r0==0)?1000:((r0==1)?100:((r0==2)?10:1));
  const int s1 = (r1==0)?1000:((r1==1)?100:((r1==2)?10:1));
  const int s2 = (r2==0)?1000:((r2==1)?100:((r2==2)?10:1));
  int f = tid;
  if (f < 1000){
    int c0=f/100, rem=f-100*c0, c1=rem/10, c2=rem-10*c1;
    int base = c0*s0 + c1*s1 + c2*s2;
    DECL_ACCP
    #pragma unroll 2
    for (int k=0;k<10;k++){
      v2f vv = *(const v2f*)&S[base + k*sm];
      v2f vs = {vv.y, vv.x};
      int kk = k*10;
      CKP(0) CKP(1) CKP(2) CKP(3) CKP(4) CKP(5) CKP(6) CKP(7) CKP(8) CKP(9)
    }
    PALLSTORE
  }
}

// Single-mode real gate. Pass ws_V for the V^T gate, ws_VT for V.
__device__ __forceinline__ void apply1_r(cxf* S, const float* __restrict__ Mt, int m, int tid){
  const int sm = (m==0)?1000:((m==1)?100:((m==2)?10:1));
  const int r0 = (m==0)?1:0, r1=(m<=1)?2:1, r2=(m<=2)?3:2;
  const int s0 = (r0==0)?1000:((r0==1)?100:((r0==2)?10:1));
  const int s1 = (r1==0)?1000:((r1==1)?100:((r1==2)?10:1));
  const int s2 = (r2==0)?1000:((r2==1)?100:((r2==2)?10:1));
  int f = tid;
  if (f < 1000){
    int c0=f/100, rem=f-100*c0, c1=rem/10, c2=rem-10*c1;
    int base = c0*s0 + c1*s1 + c2*s2;
    DECL_ACCP
    #pragma unroll 2
    for (int k=0;k<10;k++){
      v2f vv = *(const v2f*)&S[base + k*sm];
      int kk = k*10;
      RKP(0) RKP(1) RKP(2) RKP(3) RKP(4) RKP(5) RKP(6) RKP(7) RKP(8) RKP(9)
    }
    PALLSTORE
  }
}

// Conditional real gate on m2, W[n] selected by m1 digit (fiber MSD -> uniform n).
__device__ __forceinline__ void applyW(cxf* S, const float* __restrict__ Wall, int m1, int m2, int tid){
  const int sm  = (m2==0)?1000:((m2==1)?100:((m2==2)?10:1));
  const int sm1 = (m1==0)?1000:((m1==1)?100:((m1==2)?10:1));
  int ra=-1, rb=-1;
  for (int q=0;q<4;q++) if (q!=m1 && q!=m2){ if (ra<0) ra=q; else rb=q; }
  const int sa = (ra==0)?1000:((ra==1)?100:((ra==2)?10:1));
  const int sb = (rb==0)?1000:((rb==1)?100:((rb==2)?10:1));
  int f = tid;
  if (f < 1000){
    int n = f/100, rem = f-100*n, qa = rem/10, qb = rem-10*qa;
    int base = n*sm1 + qa*sa + qb*sb;
    const float* __restrict__ Mt = Wall + n*100;   // transposed W_n
    DECL_ACCP
    #pragma unroll 2
    for (int k=0;k<10;k++){
      v2f vv = *(const v2f*)&S[base + k*sm];
      int kk = k*10;
      RKP(0) RKP(1) RKP(2) RKP(3) RKP(4) RKP(5) RKP(6) RKP(7) RKP(8) RKP(9)
    }
    PALLSTORE
  }
}

// Beamsplitter via total-photon blocks; ragged c-loop, address recurrence.
__device__ __forceinline__ void applyBS(cxf* S, const cxf* __restrict__ BSp, int m1, int m2, int tid){
  int ra=-1, rb=-1;
  for (int q=0;q<4;q++) if (q!=m1 && q!=m2){ if (ra<0) ra=q; else rb=q; }
  const int sa = (ra==0)?1000:((ra==1)?100:((ra==2)?10:1));
  const int sb = (rb==0)?1000:((rb==1)?100:((rb==2)?10:1));
  const int s1 = (m1==0)?1000:((m1==1)?100:((m1==2)?10:1));
  const int s2 = (m2==0)?1000:((m2==1)?100:((m2==2)?10:1));
  const int ds = s1 - s2;
  #pragma unroll 1
  for (int w0=0; w0<2048; w0+=NTB){
    int it = w0 + tid;
    if (it < 1900){
      int bn = it/100, rest = it-100*bn;
      int ilo = bn<10?0:bn-9, ihi = bn<10?bn:9, sz = ihi-ilo+1;
      int ca = rest/10, cb = rest-10*ca;
      int base = ca*sa + cb*sb;
      const cxf* __restrict__ Bt = BSp + bn*100;   // transposed
      DECL_ACCP
      int radr = base + ilo*s1 + (bn-ilo)*s2;      // element (ilo+c, bn-ilo-c)
      int kk = 0;
      #pragma unroll 1
      for (int c=0;c<sz;c++){
        v2f vv = *(const v2f*)&S[radr];
        v2f vs = {vv.y, vv.x};
        BKP(0) BKP(1) BKP(2) BKP(3) BKP(4) BKP(5) BKP(6) BKP(7) BKP(8) BKP(9)
        radr += ds; kk += 10;
      }
      int wadr = base + ilo*s1 + (bn-ilo)*s2;
      BPALLSTORE
    }
  }
}

__global__ __launch_bounds__(NTB)
__attribute__((amdgpu_waves_per_eu(8)))
void state_kernel(const float* __restrict__ wd, const float* __restrict__ bd,
                  const float* __restrict__ wsf, float* __restrict__ out){
  extern __shared__ __align__(16) char smem[];
  cxf* S    = (cxf*)smem;                 // 10000 cxf (80000 B)
  cxf* uv   = (cxf*)(smem + 80000);       // 4*10 encoding vectors
  float* red = (float*)(smem + 80320);    // 16

  const float* __restrict__ V   = wsf;            // for V^T gate
  const float* __restrict__ VT  = wsf + 100;      // for V gate
  const float* __restrict__ W   = wsf + 200;
  const cxf*   __restrict__ BSm = (const cxf*)(wsf + 1200);
  const cxf*   __restrict__ UL  = (const cxf*)(wsf + 5000);
  const cxf*   __restrict__ uw  = (const cxf*)(wsf + 6656);

  const int tid = threadIdx.x, wv = tid>>6, lane = tid&63;
  const int b = blockIdx.x;

  if (tid < 40) uv[tid] = uw[b*40 + tid];
  __syncthreads();

  // Init: product state S = u0 (x) u1 (x) u2 (x) u3  (V0^T already folded in u0)
  for (int e=tid; e<10000; e+=NTB){
    int c0=e/1000, r_=e-1000*c0, c1=r_/100, r2_=r_-100*c1, c2=r2_/10, c3=r2_-10*c2;
    cxf A = uv[c0], B = uv[10+c1], C = uv[20+c2], D = uv[30+c3];
    float pr = A.x*B.x - A.y*B.y, pi = A.x*B.y + A.y*B.x;
    float qr = pr*C.x - pi*C.y,  qi = pr*C.y + pi*C.x;
    cxf o; o.x = qr*D.x - qi*D.y; o.y = qr*D.y + qi*D.x;
    S[e] = o;
  }
  __syncthreads();

  for (int L=0; L<2; ++L){
    // CX group a=0 (V0^T folded into u0 / UL[0]):
    applyW(S, W, 0, 1, tid); __syncthreads();
    applyW(S, W, 0, 2, tid); __syncthreads();
    applyW(S, W, 0, 3, tid); __syncthreads();
    apply1_r(S, VT, 0, tid); __syncthreads();      // V gate
    // a=1:
    apply1_r(S, V, 1, tid);  __syncthreads();      // V^T gate
    applyW(S, W, 1, 2, tid); __syncthreads();
    applyW(S, W, 1, 3, tid); __syncthreads();
    apply1_r(S, VT, 1, tid); __syncthreads();
    // a=2:
    apply1_r(S, V, 2, tid);  __syncthreads();
    applyW(S, W, 2, 3, tid); __syncthreads();
    apply1_r(S, VT, 2, tid); __syncthreads();
    // Beamsplitters:
    applyBS(S, BSm, 0, 1, tid); __syncthreads();
    applyBS(S, BSm, 1, 2, tid); __syncthreads();
    applyBS(S, BSm, 2, 3, tid); __syncthreads();
    applyBS(S, BSm, 3, 0, tid); __syncthreads();
    // Layer single-mode gates (UL[0] carries next layer's V0^T):
    for (int w=0; w<4; ++w){ apply1_c(S, UL + (L*4+w)*100, w, tid); __syncthreads(); }
  }

  float w0 = wd[0], w1 = wd[1], w2 = wd[2];
  float acc = 0.f;
  for (int e=tid; e<10000; e+=NTB){
    cxf z = S[e];
    float p = z.x*z.x + z.y*z.y;
    int n0 = e/1000, r_ = e-1000*n0, n1 = r_/100, r2_ = r_-100*n1, n2 = r2_/10;
    acc += p * ((float)n0*w0 + (float)n1*w1 + (float)n2*w2);
  }
  for (int off=32; off; off>>=1) acc += __shfl_down(acc, off, 64);
  if (lane == 0) red[wv] = acc;
  __syncthreads();
  if (tid == 0){
    float s = 0.f;
    for (int i=0;i<16;i++) s += red[i];
    out[b] = s + bd[0];
  }
}

} // anonymous namespace

extern "C" void kernel_launch(void* const* d_in, const int* in_sizes, int n_in,
                              void* d_out, int out_size, void* d_ws, size_t ws_size,
                              hipStream_t stream){
  const float* jets   = (const float*)d_in[0];
  const float* sscale = (const float*)d_in[1];
  const float* dmag   = (const float*)d_in[2];
  const float* dphase = (const float*)d_in[3];
  const float* smag   = (const float*)d_in[4];
  const float* sphase = (const float*)d_in[5];
  const float* wd     = (const float*)d_in[6];
  const float* bd     = (const float*)d_in[7];
  float* out = (float*)d_out;
  float* wsf = (float*)d_ws;
  int B = in_sizes[0] / 12;

  (void)hipFuncSetAttribute(reinterpret_cast<const void*>(&state_kernel),
                            hipFuncAttributeMaxDynamicSharedMemorySize, SMEM_BYTES);

  gates_kernel<<<8, 256, 0, stream>>>(dmag, dphase, smag, sphase, wsf);
  enc_kernel<<<B*4, 128, 0, stream>>>(jets, sscale, wsf);
  state_kernel<<<B, NTB, SMEM_BYTES, stream>>>(wd, bd, wsf, out);
}